// Round 11
// baseline (435.558 us; speedup 1.0000x reference)
//
#include <hip/hip_runtime.h>

// ---------------------------------------------------------------------------
// SLAYER SNN on MI355X — layer 1 on i8 MATRIX CORES, exact integer limbs.
//   q[o,f] = rint(W1[o,f]*2^27) == l0 + 256 l1 + 65536 l2 + 2^24 l3 (signed
//   i8 limbs, exact). z*2^27 = sum_l 2^(8l) * (limb_l GEMM x), x in {0,1} i8,
//   v_mfma_i32_32x32x32_i8 accumulate (exact, |p| <= ~2e5 << 2^31).
//   M is LIMB-INTERLEAVED: m = o*4 + l. With the C/D mapping
//   row=(r&3)+8*(r>>2)+4*(lane>>5), lane (h=lane>>5) r-quad q holds limbs
//   0..3 of o_loc=2q+h in acc[4q..4q+3] -> limbs combine IN-REGISTER to one
//   i64 (exact) -> P is 16 MB i64 (was 32 MB i32 planes).
//   z remains BIT-IDENTICAL to the proven integer path.
// Occupancy fix vs round 10: n-tile 64 t (1 ng/wave) -> grid (40,13,2) =
// 1040 blocks = 4160 waves = 4.1/SIMD (was 1.6) to feed the matrix pipe.
// Operands pre-swizzled in GLOBAL memory to exact fragment order -> GEMM has
// NO LDS, NO barriers. Layers 2/3 keep the sparse path; spike via exact E,G
// recurrence (round-9 proven).
// ---------------------------------------------------------------------------

#define B   8
#define T   300
#define F0  16384
#define O1  410
#define O2  240
#define OP2 240
#define O3  10
#define OP3 16
#define W1M 7
#define W2M 4
#define NCOLS (B*T)      // 2400
#define LCAP 2048
#define PPLC ((size_t)416 * NCOLS)   // i64 elements per kc plane

typedef int  int32x4  __attribute__((ext_vector_type(4)));
typedef int  int32x16 __attribute__((ext_vector_type(16)));

// ---------------------------------------------------------------------------
// Bswz builder: x[b][f][t] f32 -> swizzled i8 B operand.
//   chunk(b,kit): 10 ng x 2048 B; word = ks*64 + (t&31) + 32*hb; byte i = k&15
// ---------------------------------------------------------------------------
__global__ __launch_bounds__(256) void transpose_x_kernel(
    const float* __restrict__ X, char* __restrict__ Bswz)
{
    __shared__ float tileT[64][65];    // [t-local][f-local]
    int tt = blockIdx.x;               // t-tile (0..4)
    int kit = blockIdx.y;              // f-word (0..255)
    int b  = blockIdx.z;
    int t0 = tt * 64, f0 = kit * 64;
    int tid = threadIdx.x;

    const float* Xb = X + ((size_t)b * F0 + f0) * T;
    int fl = tid >> 4;
    int tq = (tid & 15) * 4;
    #pragma unroll
    for (int i = 0; i < 4; ++i) {
        int fr = fl + i * 16;
        int t  = t0 + tq;
        float4 v = make_float4(0.f, 0.f, 0.f, 0.f);
        if (t < T) v = *(const float4*)(Xb + (size_t)fr * T + t);
        tileT[tq + 0][fr] = v.x;
        tileT[tq + 1][fr] = v.y;
        tileT[tq + 2][fr] = v.z;
        tileT[tq + 3][fr] = v.w;
    }
    __syncthreads();

    int tl = tid & 63;
    int fg = tid >> 6;                 // 16-f group (0..3)
    unsigned d[4] = {0u, 0u, 0u, 0u};
    #pragma unroll
    for (int j = 0; j < 16; ++j) {
        unsigned bit = (tileT[tl][fg * 16 + j] != 0.0f) ? 1u : 0u;
        d[j >> 2] |= bit << (8 * (j & 3));
    }
    int ng   = (t0 + tl) >> 5;
    int word = (fg >> 1) * 64 + (tl & 31) + 32 * (fg & 1);
    size_t addr = ((size_t)(b * 256 + kit) * 10 + ng) * 2048 + (size_t)word * 16;
    *(int32x4*)(Bswz + addr) = (int32x4){(int)d[0], (int)d[1], (int)d[2], (int)d[3]};
}

// ---------------------------------------------------------------------------
// Aswz builder: W1 -> 4 signed i8 limbs, limb-interleaved m = o*4+l.
// Thread owns 16 consecutive f = one full 16B word per limb (4x 16B stores).
//   addr = ((mt*256+kit)*4 + g)*2048 + (ks*64 + row + 32*hb)*16
//   mt=m>>7, r=m&127, g=r>>5, row=r&31; kit=f0/64, ks=(f0>>5)&1, hb=(f0>>4)&1
// ---------------------------------------------------------------------------
__global__ __launch_bounds__(256) void quant_limb_kernel(
    const float* __restrict__ W, char* __restrict__ Aswz)
{
    int o  = blockIdx.y;               // 0..415
    int f0 = (blockIdx.x * 256 + threadIdx.x) * 16;

    float w[16];
    if (o < O1) {
        #pragma unroll
        for (int e = 0; e < 16; e += 4)
            *(float4*)&w[e] = *(const float4*)(W + (size_t)o * F0 + f0 + e);
    } else {
        #pragma unroll
        for (int e = 0; e < 16; ++e) w[e] = 0.0f;
    }

    unsigned pk[4][4] = {{0,0,0,0},{0,0,0,0},{0,0,0,0},{0,0,0,0}};
    #pragma unroll
    for (int e = 0; e < 16; ++e) {
        int q = (int)__double2ll_rn((double)w[e] * 134217728.0);   // 2^27
        int l0 = (int)(signed char)(q & 255);  q = (q - l0) >> 8;
        int l1 = (int)(signed char)(q & 255);  q = (q - l1) >> 8;
        int l2 = (int)(signed char)(q & 255);  int l3 = (q - l2) >> 8;
        pk[0][e >> 2] |= (unsigned)(l0 & 255) << (8 * (e & 3));
        pk[1][e >> 2] |= (unsigned)(l1 & 255) << (8 * (e & 3));
        pk[2][e >> 2] |= (unsigned)(l2 & 255) << (8 * (e & 3));
        pk[3][e >> 2] |= (unsigned)(l3 & 255) << (8 * (e & 3));
    }

    int kit = f0 >> 6, ks = (f0 >> 5) & 1, hb = (f0 >> 4) & 1;
    #pragma unroll
    for (int l = 0; l < 4; ++l) {
        int m = o * 4 + l;
        int mt = m >> 7, r = m & 127, g = r >> 5, row = r & 31;
        int word = ks * 64 + row + 32 * hb;
        size_t addr = ((size_t)(mt * 256 + kit) * 4 + g) * 2048 + (size_t)word * 16;
        *(int32x4*)(Aswz + addr) =
            (int32x4){(int)pk[l][0], (int)pk[l][1], (int)pk[l][2], (int)pk[l][3]};
    }
}

__global__ __launch_bounds__(256) void quant_small_kernel(
    const float* __restrict__ W, int* __restrict__ QT, int O, int F, int OPAD)
{
    int idx = blockIdx.x * 256 + threadIdx.x;
    if (idx >= F * OPAD) return;
    int f = idx / OPAD, o = idx - f * OPAD;
    double v = (o < O) ? (double)W[(size_t)o * F + f] : 0.0;
    QT[idx] = (int)__double2ll_rn(v * 67108864.0);       // 2^26
}

// ---------------------------------------------------------------------------
// LDS-free i8 MFMA GEMM. Grid (b*5+ngp, mt, kc) = (40,13,2); 4 waves
// (wm x wn); wave = 2 m-frags x 1 ng x K/2. In-register limb combine -> i64.
// ---------------------------------------------------------------------------
__global__ __launch_bounds__(256) void mfma_gemm_kernel(
    const char* __restrict__ Aswz, const char* __restrict__ Bswz,
    long long* __restrict__ Pc)
{
    int bn = blockIdx.x;
    int mt = blockIdx.y;               // 0..12
    int kc = blockIdx.z;               // 0..1
    int b = bn / 5, ngp = bn % 5;

    int tid = threadIdx.x;
    int lane = tid & 63, wv = tid >> 6;
    int wm = wv >> 1, wn = wv & 1;
    int ng = ngp * 2 + wn;

    const char* Ab = Aswz + ((size_t)(mt * 256 + kc * 128) * 4 + wm * 2) * 2048
                          + (size_t)lane * 16;
    const char* Bb = Bswz + ((size_t)(b * 256 + kc * 128) * 10 + ng) * 2048
                          + (size_t)lane * 16;

    int32x16 acc[2];
    #pragma unroll
    for (int fm = 0; fm < 2; ++fm)
        acc[fm] = (int32x16){0,0,0,0,0,0,0,0,0,0,0,0,0,0,0,0};

    #pragma unroll 2
    for (int it = 0; it < 128; ++it) {
        int32x4 a00 = *(const int32x4*)(Ab);
        int32x4 a01 = *(const int32x4*)(Ab + 1024);
        int32x4 a10 = *(const int32x4*)(Ab + 2048);
        int32x4 a11 = *(const int32x4*)(Ab + 3072);
        int32x4 b0  = *(const int32x4*)(Bb);
        int32x4 b1  = *(const int32x4*)(Bb + 1024);

        acc[0] = __builtin_amdgcn_mfma_i32_32x32x32_i8(a00, b0, acc[0], 0, 0, 0);
        acc[1] = __builtin_amdgcn_mfma_i32_32x32x32_i8(a10, b0, acc[1], 0, 0, 0);
        acc[0] = __builtin_amdgcn_mfma_i32_32x32x32_i8(a01, b1, acc[0], 0, 0, 0);
        acc[1] = __builtin_amdgcn_mfma_i32_32x32x32_i8(a11, b1, acc[1], 0, 0, 0);

        Ab += 8192;        // 4 g-chunks * 2048
        Bb += 20480;       // 10 ng * 2048
    }

    int col = lane & 31, h = lane >> 5;
    int t = ng * 32 + col;
    if (t < T) {
        long long* Pk = Pc + (size_t)kc * PPLC + (size_t)b * T + t;
        #pragma unroll
        for (int fm = 0; fm < 2; ++fm) {
            int obase = mt * 32 + wm * 16 + fm * 8;
            #pragma unroll
            for (int q = 0; q < 4; ++q) {
                int o = obase + 2 * q + h;
                long long s = (long long)acc[fm][4 * q]
                            + ((long long)acc[fm][4 * q + 1] << 8)
                            + ((long long)acc[fm][4 * q + 2] << 16)
                            + ((long long)acc[fm][4 * q + 3] << 24);
                Pk[(size_t)o * NCOLS] = s;
            }
        }
    }
}

// ---------------------------------------------------------------------------
// Combine kc planes (exact i64) + psp conv for layer 1.
// ---------------------------------------------------------------------------
__global__ __launch_bounds__(320) void redpsp_mfma_kernel(
    const long long* __restrict__ Pc, double* __restrict__ U)
{
    __shared__ double zs[16][304];
    __shared__ double eps[100];
    int og = blockIdx.x, b = blockIdx.y;
    int o0 = og * 16;
    int tid = threadIdx.x;
    const double sc27 = 1.0 / 134217728.0;

    if (tid < 100) {
        double td = (double)tid;
        eps[tid] = (td / 10.0) * exp(1.0 - td / 10.0);
    }
    if (tid < T) {
        size_t col = (size_t)b * T + tid;
        #pragma unroll 4
        for (int ol = 0; ol < 16; ++ol) {
            int o = o0 + ol;
            long long s = Pc[(size_t)o * NCOLS + col]
                        + Pc[PPLC + (size_t)o * NCOLS + col];
            zs[ol][tid] = (double)s * sc27;
        }
    }
    __syncthreads();

    if (tid < T) {
        double sum[16];
        #pragma unroll
        for (int o = 0; o < 16; ++o) sum[o] = 0.0;
        int kmax = tid < 99 ? tid : 99;
        for (int k = 0; k <= kmax; ++k) {
            double e = eps[k];
            #pragma unroll
            for (int o = 0; o < 16; ++o)
                sum[o] = fma(e, zs[o][tid - k], sum[o]);
        }
        #pragma unroll
        for (int o = 0; o < 16; ++o) {
            int oo = o0 + o;
            if (oo < O1) U[((size_t)b * O1 + oo) * T + tid] = sum[o];
        }
    }
}

// ---------------------------------------------------------------------------
// Sparse integer GEMM for layers 2/3 (proven).
// ---------------------------------------------------------------------------
__global__ __launch_bounds__(128) void sparse_gemm_kernel(
    const int* __restrict__ QT, const unsigned long long* __restrict__ cmask,
    int* __restrict__ Z, int OPAD, int W, int CW, int cshift)
{
    __shared__ int lf[LCAP];
    __shared__ int wsum[2];

    int chunk = blockIdx.x & ((1 << cshift) - 1);
    int col   = blockIdx.x >> cshift;
    int tid   = threadIdx.x;

    int wbase = col * W + chunk * CW;
    unsigned long long w0 = (2 * tid     < CW) ? cmask[wbase + 2 * tid]     : 0ULL;
    unsigned long long w1 = (2 * tid + 1 < CW) ? cmask[wbase + 2 * tid + 1] : 0ULL;
    int my = __popcll(w0) + __popcll(w1);

    int scan = my;
    #pragma unroll
    for (int d = 1; d < 64; d <<= 1) {
        int v = __shfl_up(scan, d);
        if ((tid & 63) >= d) scan += v;
    }
    if ((tid & 63) == 63) wsum[tid >> 6] = scan;
    __syncthreads();
    int off = ((tid >= 64) ? wsum[0] : 0) + scan - my;
    int n = wsum[0] + wsum[1];

    int f0e = (chunk * CW + 2 * tid) * 64;
    unsigned long long m = w0;
    while (m) {
        int bit = __ffsll(m) - 1;
        if (off < LCAP) lf[off] = (f0e + bit) * OPAD;
        ++off; m &= m - 1;
    }
    m = w1; f0e += 64;
    while (m) {
        int bit = __ffsll(m) - 1;
        if (off < LCAP) lf[off] = (f0e + bit) * OPAD;
        ++off; m &= m - 1;
    }
    __syncthreads();
    if (n > LCAP) n = LCAP;

    if (tid * 4 < OPAD) {
        int o = tid * 4;
        const int* bq = QT + o;
        int a0 = 0, a1 = 0, a2 = 0, a3 = 0;
        int i = 0;
        for (; i + 8 <= n; i += 8) {
            int4 ia = *(const int4*)&lf[i];
            int4 ib = *(const int4*)&lf[i + 4];
            int e0 = __builtin_amdgcn_readfirstlane(ia.x);
            int e1 = __builtin_amdgcn_readfirstlane(ia.y);
            int e2 = __builtin_amdgcn_readfirstlane(ia.z);
            int e3 = __builtin_amdgcn_readfirstlane(ia.w);
            int e4 = __builtin_amdgcn_readfirstlane(ib.x);
            int e5 = __builtin_amdgcn_readfirstlane(ib.y);
            int e6 = __builtin_amdgcn_readfirstlane(ib.z);
            int e7 = __builtin_amdgcn_readfirstlane(ib.w);
            int4 q0 = *(const int4*)(bq + e0);
            int4 q1 = *(const int4*)(bq + e1);
            int4 q2 = *(const int4*)(bq + e2);
            int4 q3 = *(const int4*)(bq + e3);
            int4 q4 = *(const int4*)(bq + e4);
            int4 q5 = *(const int4*)(bq + e5);
            int4 q6 = *(const int4*)(bq + e6);
            int4 q7 = *(const int4*)(bq + e7);
            a0 += q0.x; a1 += q0.y; a2 += q0.z; a3 += q0.w;
            a0 += q1.x; a1 += q1.y; a2 += q1.z; a3 += q1.w;
            a0 += q2.x; a1 += q2.y; a2 += q2.z; a3 += q2.w;
            a0 += q3.x; a1 += q3.y; a2 += q3.z; a3 += q3.w;
            a0 += q4.x; a1 += q4.y; a2 += q4.z; a3 += q4.w;
            a0 += q5.x; a1 += q5.y; a2 += q5.z; a3 += q5.w;
            a0 += q6.x; a1 += q6.y; a2 += q6.z; a3 += q6.w;
            a0 += q7.x; a1 += q7.y; a2 += q7.z; a3 += q7.w;
        }
        for (; i < n; ++i) {
            int e = __builtin_amdgcn_readfirstlane(lf[i]);
            int4 q = *(const int4*)(bq + e);
            a0 += q.x; a1 += q.y; a2 += q.z; a3 += q.w;
        }
        int* zb = Z + ((size_t)chunk * NCOLS + col) * OPAD + o;
        *(int4*)zb = make_int4(a0, a1, a2, a3);
    }
}

template<int NCHUNK>
__global__ __launch_bounds__(320) void redpsp_kernel(
    const int* __restrict__ Z, double* __restrict__ U,
    int OPAD, int O, double scale)
{
    __shared__ double zs[16][304];
    __shared__ double eps[100];
    int og = blockIdx.x, b = blockIdx.y;
    int o0 = og * 16;
    int tid = threadIdx.x;

    if (tid < 100) {
        double td = (double)tid;
        eps[tid] = (td / 10.0) * exp(1.0 - td / 10.0);
    }
    int ol = tid & 15, tg = tid >> 4;
    #pragma unroll 3
    for (int tt = 0; tt < 15; ++tt) {
        int t = tg + tt * 20;
        const int* zp = Z + ((size_t)(b * T + t)) * OPAD + o0 + ol;
        long long s = 0;
        #pragma unroll
        for (int c = 0; c < NCHUNK; ++c)
            s += zp[(size_t)c * NCOLS * OPAD];
        zs[ol][t] = (double)s * scale;
    }
    __syncthreads();

    if (tid < T) {
        double sum[16];
        #pragma unroll
        for (int o = 0; o < 16; ++o) sum[o] = 0.0;
        int kmax = tid < 99 ? tid : 99;
        for (int k = 0; k <= kmax; ++k) {
            double e = eps[k];
            #pragma unroll
            for (int o = 0; o < 16; ++o)
                sum[o] = fma(e, zs[o][tid - k], sum[o]);
        }
        #pragma unroll
        for (int o = 0; o < 16; ++o) {
            int oo = o0 + o;
            if (oo < O) U[((size_t)b * O + oo) * T + tid] = sum[o];
        }
    }
}

// ---------------------------------------------------------------------------
// Spike LIF via exact finite-window recurrence, dbuf-staged (round-9 proven).
// ---------------------------------------------------------------------------
#define SPIKE_STAGE(BUF, T0, TIDX, NT)                                        \
    { int cl_ = T - (T0); if (cl_ > 64) cl_ = 64;                             \
      for (int idx = (TIDX); idx < 64 * 64; idx += (NT)) {                    \
        int r_ = idx >> 6, tl_ = idx & 63;                                    \
        int orow_ = w * 64 + r_; if (orow_ >= O) orow_ = O - 1;               \
        if (tl_ < cl_)                                                        \
            us[BUF][r_][tl_] = U[((size_t)b * O + orow_) * T + (T0) + tl_]; } }

__global__ __launch_bounds__(256) void spike_kernel(
    const double* __restrict__ U, unsigned long long* __restrict__ smask,
    float* __restrict__ sout, int O, int words)
{
    __shared__ double us[2][64][65];
    int w = blockIdx.x, b = blockIdx.y;
    int tid = threadIdx.x;
    int lane = tid & 63;
    int o = w * 64 + lane;
    bool active = (o < O);

    const double alpha = exp(-0.5);
    const double A31   = exp(-15.5);
    const double c0    = -10.0 * exp(1.0);

    SPIKE_STAGE(0, 0, tid, 256);
    __syncthreads();

    double E = 0.0, G = 0.0;
    unsigned hist = 0u;
    float* so = (sout && active) ? sout + ((size_t)b * O + o) * T : (float*)0;

    const int NCH = (T + 63) / 64;
    for (int c = 0; c < NCH; ++c) {
        int cur = c & 1;
        if (tid >= 64) {
            if (c + 1 < NCH) SPIKE_STAGE(cur ^ 1, (c + 1) * 64, tid - 64, 192);
        } else {
            int t0 = c * 64;
            int cl = T - t0; if (cl > 64) cl = 64;
            for (int tl = 0; tl < cl; ++tl) {
                double uval = active ? us[cur][lane][tl] : -1.0e300;
                double v = uval + c0 * G;
                bool sp = (v >= 10.0);
                unsigned long long bal = __ballot(sp);
                if (smask && lane == 0)
                    smask[((size_t)b * T + t0 + tl) * words + w] = bal;
                if (so) so[t0 + tl] = sp ? 1.0f : 0.0f;

                double sN  = sp ? 1.0 : 0.0;
                double s31 = ((hist >> 30) & 1u) ? 1.0 : 0.0;
                double Em  = E - A31 * s31;
                double Gm  = G - 31.0 * A31 * s31;
                G = alpha * (sN + Gm + Em);
                E = alpha * (sN + Em);
                hist = (hist << 1) | (sp ? 1u : 0u);
            }
        }
        __syncthreads();
    }
}

// ---------------------------------------------------------------------------
extern "C" void kernel_launch(void* const* d_in, const int* in_sizes, int n_in,
                              void* d_out, int out_size, void* d_ws, size_t ws_size,
                              hipStream_t stream)
{
    const float* x  = (const float*)d_in[0];
    const float* W1 = (const float*)d_in[1];
    const float* W2 = (const float*)d_in[2];
    const float* W3 = (const float*)d_in[3];
    float* out = (float*)d_out;

    const size_t sz_Aswz = (size_t)13 * 256 * 4 * 2048;      // 27.26 MB
    const size_t sz_Bswz = (size_t)8 * 256 * 10 * 2048;      // 41.94 MB
    const size_t sz_Pc   = (size_t)2 * PPLC * 8;             // 15.97 MB
    const size_t sz_u1   = (size_t)B * O1 * T * 8;           //  7.87 MB
    const size_t sz_Q2T  = (size_t)O1 * OP2 * 4;
    const size_t sz_Q3T  = (size_t)O2 * OP3 * 4;

    char* p = (char*)d_ws;
    char*      Aswz = p;                p += sz_Aswz;
    char*      Bswz = p;                p += sz_Bswz;
    long long* Pc   = (long long*)p;  char* pa = p;  p += sz_Pc;
    double*    u1   = (double*)p;       p += sz_u1;
    int*       Q2T  = (int*)p;          p += sz_Q2T;
    int*       Q3T  = (int*)p;          p += sz_Q3T;
    // Aliased into Pc's region (Pc dead after redpsp_mfma):
    int*                z2     = (int*)pa;                pa += (size_t)NCOLS * OP2 * 4;
    double*             u2     = (double*)pa;             pa += (size_t)B * O2 * T * 8;
    int*                z3     = (int*)pa;                pa += (size_t)NCOLS * OP3 * 4;
    double*             u3     = (double*)pa;             pa += (size_t)B * O3 * T * 8;
    unsigned long long* smask1 = (unsigned long long*)pa; pa += (size_t)NCOLS * W1M * 8;
    unsigned long long* smask2 = (unsigned long long*)pa; pa += (size_t)NCOLS * W2M * 8;

    const double sc26 = 1.0 / 67108864.0;

    // --- prep ---
    transpose_x_kernel<<<dim3(5, 256, B), dim3(256), 0, stream>>>(x, Bswz);
    quant_limb_kernel<<<dim3(4, 416), dim3(256), 0, stream>>>(W1, Aswz);
    quant_small_kernel<<<dim3((O1 * OP2 + 255) / 256), dim3(256), 0, stream>>>(
        W2, Q2T, O2, O1, OP2);
    quant_small_kernel<<<dim3((O2 * OP3 + 255) / 256), dim3(256), 0, stream>>>(
        W3, Q3T, O3, O2, OP3);

    // --- layer 1 (MFMA) ---
    mfma_gemm_kernel<<<dim3(40, 13, 2), dim3(256), 0, stream>>>(Aswz, Bswz, Pc);
    redpsp_mfma_kernel<<<dim3(26, B), dim3(320), 0, stream>>>(Pc, u1);
    spike_kernel<<<dim3(W1M, B), dim3(256), 0, stream>>>(u1, smask1, (float*)0, O1, W1M);

    // --- layer 2 (sparse) ---
    sparse_gemm_kernel<<<dim3(NCOLS), dim3(128), 0, stream>>>(
        Q2T, smask1, z2, OP2, W1M, W1M, 0);
    redpsp_kernel<1><<<dim3(OP2 / 16, B), dim3(320), 0, stream>>>(
        z2, u2, OP2, O2, sc26);
    spike_kernel<<<dim3(W2M, B), dim3(256), 0, stream>>>(u2, smask2, (float*)0, O2, W2M);

    // --- layer 3 (sparse) ---
    sparse_gemm_kernel<<<dim3(NCOLS), dim3(128), 0, stream>>>(
        Q3T, smask2, z3, OP3, W2M, W2M, 0);
    redpsp_kernel<1><<<dim3(OP3 / 16, B), dim3(320), 0, stream>>>(
        z3, u3, OP3, O3, sc26);
    spike_kernel<<<dim3(1, B), dim3(256), 0, stream>>>(u3, (unsigned long long*)0, out, O3, 0);
}

// Round 12
// 368.215 us; speedup vs baseline: 1.1829x; 1.1829x over previous
//
#include <hip/hip_runtime.h>

// ---------------------------------------------------------------------------
// SLAYER SNN on MI355X — layer 1 on i8 MATRIX CORES, exact integer limbs.
//   q[o,f] = rint(W1[o,f]*2^27) == l0 + 256 l1 + 65536 l2 + 2^24 l3 (signed
//   i8 limbs, exact). z*2^27 = sum_l 2^(8l) * (limb_l GEMM x), x in {0,1} i8,
//   v_mfma_i32_32x32x32_i8 accumulate (exact). M limb-interleaved (m=o*4+l):
//   C/D row=(r&3)+8*(r>>2)+4*(lane>>5) puts all 4 limbs of o_loc=2q+h in
//   acc quad q -> limbs combine IN-REGISTER to one i64 (exact).
//   z BIT-IDENTICAL to the proven integer path.
// Round 12 (post round-11 regression): keep round-10's 6-independent-acc
// wave shape (12/8 MFMA per iter — ILP feeds the matrix pipe), get waves
// from a K-SPLIT (kc=4) which does NOT duplicate A traffic:
// grid (16,13,4)=832 blocks=3.25 waves/SIMD (round 10: 1.6 at 129us).
// Layers 2/3 sparse path; spike via exact E,G recurrence (proven).
// ---------------------------------------------------------------------------

#define B   8
#define T   300
#define F0  16384
#define O1  410
#define O2  240
#define OP2 240
#define O3  10
#define OP3 16
#define W1M 7
#define W2M 4
#define NCOLS (B*T)      // 2400
#define LCAP 2048
#define PPLC ((size_t)416 * NCOLS)   // i64 elements per kc plane

typedef int  int32x4  __attribute__((ext_vector_type(4)));
typedef int  int32x16 __attribute__((ext_vector_type(16)));

// ---------------------------------------------------------------------------
// Bswz builder: x[b][f][t] f32 -> swizzled i8 B operand.
// ---------------------------------------------------------------------------
__global__ __launch_bounds__(256) void transpose_x_kernel(
    const float* __restrict__ X, char* __restrict__ Bswz)
{
    __shared__ float tileT[64][65];
    int tt = blockIdx.x;
    int kit = blockIdx.y;
    int b  = blockIdx.z;
    int t0 = tt * 64, f0 = kit * 64;
    int tid = threadIdx.x;

    const float* Xb = X + ((size_t)b * F0 + f0) * T;
    int fl = tid >> 4;
    int tq = (tid & 15) * 4;
    #pragma unroll
    for (int i = 0; i < 4; ++i) {
        int fr = fl + i * 16;
        int t  = t0 + tq;
        float4 v = make_float4(0.f, 0.f, 0.f, 0.f);
        if (t < T) v = *(const float4*)(Xb + (size_t)fr * T + t);
        tileT[tq + 0][fr] = v.x;
        tileT[tq + 1][fr] = v.y;
        tileT[tq + 2][fr] = v.z;
        tileT[tq + 3][fr] = v.w;
    }
    __syncthreads();

    int tl = tid & 63;
    int fg = tid >> 6;
    unsigned d[4] = {0u, 0u, 0u, 0u};
    #pragma unroll
    for (int j = 0; j < 16; ++j) {
        unsigned bit = (tileT[tl][fg * 16 + j] != 0.0f) ? 1u : 0u;
        d[j >> 2] |= bit << (8 * (j & 3));
    }
    int ng   = (t0 + tl) >> 5;
    int word = (fg >> 1) * 64 + (tl & 31) + 32 * (fg & 1);
    size_t addr = ((size_t)(b * 256 + kit) * 10 + ng) * 2048 + (size_t)word * 16;
    *(int32x4*)(Bswz + addr) = (int32x4){(int)d[0], (int)d[1], (int)d[2], (int)d[3]};
}

// ---------------------------------------------------------------------------
// Aswz builder: W1 -> 4 signed i8 limbs, limb-interleaved m = o*4+l.
// ---------------------------------------------------------------------------
__global__ __launch_bounds__(256) void quant_limb_kernel(
    const float* __restrict__ W, char* __restrict__ Aswz)
{
    int o  = blockIdx.y;
    int f0 = (blockIdx.x * 256 + threadIdx.x) * 16;

    float w[16];
    if (o < O1) {
        #pragma unroll
        for (int e = 0; e < 16; e += 4)
            *(float4*)&w[e] = *(const float4*)(W + (size_t)o * F0 + f0 + e);
    } else {
        #pragma unroll
        for (int e = 0; e < 16; ++e) w[e] = 0.0f;
    }

    unsigned pk[4][4] = {{0,0,0,0},{0,0,0,0},{0,0,0,0},{0,0,0,0}};
    #pragma unroll
    for (int e = 0; e < 16; ++e) {
        int q = (int)__double2ll_rn((double)w[e] * 134217728.0);   // 2^27
        int l0 = (int)(signed char)(q & 255);  q = (q - l0) >> 8;
        int l1 = (int)(signed char)(q & 255);  q = (q - l1) >> 8;
        int l2 = (int)(signed char)(q & 255);  int l3 = (q - l2) >> 8;
        pk[0][e >> 2] |= (unsigned)(l0 & 255) << (8 * (e & 3));
        pk[1][e >> 2] |= (unsigned)(l1 & 255) << (8 * (e & 3));
        pk[2][e >> 2] |= (unsigned)(l2 & 255) << (8 * (e & 3));
        pk[3][e >> 2] |= (unsigned)(l3 & 255) << (8 * (e & 3));
    }

    int kit = f0 >> 6, ks = (f0 >> 5) & 1, hb = (f0 >> 4) & 1;
    #pragma unroll
    for (int l = 0; l < 4; ++l) {
        int m = o * 4 + l;
        int mt = m >> 7, r = m & 127, g = r >> 5, row = r & 31;
        int word = ks * 64 + row + 32 * hb;
        size_t addr = ((size_t)(mt * 256 + kit) * 4 + g) * 2048 + (size_t)word * 16;
        *(int32x4*)(Aswz + addr) =
            (int32x4){(int)pk[l][0], (int)pk[l][1], (int)pk[l][2], (int)pk[l][3]};
    }
}

__global__ __launch_bounds__(256) void quant_small_kernel(
    const float* __restrict__ W, int* __restrict__ QT, int O, int F, int OPAD)
{
    int idx = blockIdx.x * 256 + threadIdx.x;
    if (idx >= F * OPAD) return;
    int f = idx / OPAD, o = idx - f * OPAD;
    double v = (o < O) ? (double)W[(size_t)o * F + f] : 0.0;
    QT[idx] = (int)__double2ll_rn(v * 67108864.0);       // 2^26
}

// ---------------------------------------------------------------------------
// LDS-free i8 MFMA GEMM, round-10 wave shape + kc=4 K-split.
// Grid (bh=16, mt=13, kc=4); block 256 = 4 waves (2m x 2n); per-block 64 its.
// Wave wn=0: ng 0..2 (3 frags), wn=1: ng 3..4 (2 frags) of its half.
// ---------------------------------------------------------------------------
__global__ __launch_bounds__(256) void mfma_gemm_kernel(
    const char* __restrict__ Aswz, const char* __restrict__ Bswz,
    long long* __restrict__ Pc)
{
    int bh = blockIdx.x;               // b*2 + half
    int mt = blockIdx.y;               // 0..12
    int kc = blockIdx.z;               // 0..3
    int b = bh >> 1, half = bh & 1;

    int tid = threadIdx.x;
    int lane = tid & 63, wv = tid >> 6;
    int wm = wv >> 1, wn = wv & 1;
    int ng0 = wn * 3;
    int nfr = wn ? 2 : 3;              // wave-uniform

    const char* Ab = Aswz + ((size_t)(mt * 256 + kc * 64) * 4 + wm * 2) * 2048
                          + (size_t)lane * 16;
    const char* Bb = Bswz + ((size_t)(b * 256 + kc * 64) * 10 + half * 5 + ng0) * 2048
                          + (size_t)lane * 16;

    int32x16 acc[2][3];
    #pragma unroll
    for (int fm = 0; fm < 2; ++fm)
        #pragma unroll
        for (int fn = 0; fn < 3; ++fn)
            acc[fm][fn] = (int32x16){0,0,0,0,0,0,0,0,0,0,0,0,0,0,0,0};

    #pragma unroll 2
    for (int it = 0; it < 64; ++it) {
        int32x4 a[2][2], bv[3][2];
        #pragma unroll
        for (int fm = 0; fm < 2; ++fm)
            #pragma unroll
            for (int ks = 0; ks < 2; ++ks)
                a[fm][ks] = *(const int32x4*)(Ab + fm * 2048 + ks * 1024);
        #pragma unroll
        for (int fn = 0; fn < 3; ++fn)
            if (fn < nfr)
                #pragma unroll
                for (int ks = 0; ks < 2; ++ks)
                    bv[fn][ks] = *(const int32x4*)(Bb + fn * 2048 + ks * 1024);

        #pragma unroll
        for (int ks = 0; ks < 2; ++ks)
            #pragma unroll
            for (int fm = 0; fm < 2; ++fm)
                #pragma unroll
                for (int fn = 0; fn < 3; ++fn)
                    if (fn < nfr)
                        acc[fm][fn] = __builtin_amdgcn_mfma_i32_32x32x32_i8(
                            a[fm][ks], bv[fn][ks], acc[fm][fn], 0, 0, 0);

        Ab += 8192;        // 4 g-groups * 2048
        Bb += 20480;       // 10 ng * 2048
    }

    // In-register limb combine -> i64 plane write.
    int col = lane & 31, h = lane >> 5;
    long long* Pk = Pc + (size_t)kc * PPLC + (size_t)b * T;
    #pragma unroll
    for (int fm = 0; fm < 2; ++fm) {
        #pragma unroll
        for (int fn = 0; fn < 3; ++fn) {
            if (fn >= nfr) continue;
            int t = (half * 5 + ng0 + fn) * 32 + col;
            if (t >= T) continue;
            int obase = mt * 32 + wm * 16 + fm * 8;
            #pragma unroll
            for (int q = 0; q < 4; ++q) {
                int o = obase + 2 * q + h;
                long long s = (long long)acc[fm][fn][4 * q]
                            + ((long long)acc[fm][fn][4 * q + 1] << 8)
                            + ((long long)acc[fm][fn][4 * q + 2] << 16)
                            + ((long long)acc[fm][fn][4 * q + 3] << 24);
                Pk[(size_t)o * NCOLS + t] = s;
            }
        }
    }
}

// ---------------------------------------------------------------------------
// Combine 4 kc planes (exact i64) + psp conv for layer 1.
// ---------------------------------------------------------------------------
__global__ __launch_bounds__(320) void redpsp_mfma_kernel(
    const long long* __restrict__ Pc, double* __restrict__ U)
{
    __shared__ double zs[16][304];
    __shared__ double eps[100];
    int og = blockIdx.x, b = blockIdx.y;
    int o0 = og * 16;
    int tid = threadIdx.x;
    const double sc27 = 1.0 / 134217728.0;

    if (tid < 100) {
        double td = (double)tid;
        eps[tid] = (td / 10.0) * exp(1.0 - td / 10.0);
    }
    if (tid < T) {
        size_t col = (size_t)b * T + tid;
        #pragma unroll 4
        for (int ol = 0; ol < 16; ++ol) {
            int o = o0 + ol;
            size_t idx = (size_t)o * NCOLS + col;
            long long s = Pc[idx] + Pc[PPLC + idx]
                        + Pc[2 * PPLC + idx] + Pc[3 * PPLC + idx];
            zs[ol][tid] = (double)s * sc27;
        }
    }
    __syncthreads();

    if (tid < T) {
        double sum[16];
        #pragma unroll
        for (int o = 0; o < 16; ++o) sum[o] = 0.0;
        int kmax = tid < 99 ? tid : 99;
        for (int k = 0; k <= kmax; ++k) {
            double e = eps[k];
            #pragma unroll
            for (int o = 0; o < 16; ++o)
                sum[o] = fma(e, zs[o][tid - k], sum[o]);
        }
        #pragma unroll
        for (int o = 0; o < 16; ++o) {
            int oo = o0 + o;
            if (oo < O1) U[((size_t)b * O1 + oo) * T + tid] = sum[o];
        }
    }
}

// ---------------------------------------------------------------------------
// Sparse integer GEMM for layers 2/3 (proven).
// ---------------------------------------------------------------------------
__global__ __launch_bounds__(128) void sparse_gemm_kernel(
    const int* __restrict__ QT, const unsigned long long* __restrict__ cmask,
    int* __restrict__ Z, int OPAD, int W, int CW, int cshift)
{
    __shared__ int lf[LCAP];
    __shared__ int wsum[2];

    int chunk = blockIdx.x & ((1 << cshift) - 1);
    int col   = blockIdx.x >> cshift;
    int tid   = threadIdx.x;

    int wbase = col * W + chunk * CW;
    unsigned long long w0 = (2 * tid     < CW) ? cmask[wbase + 2 * tid]     : 0ULL;
    unsigned long long w1 = (2 * tid + 1 < CW) ? cmask[wbase + 2 * tid + 1] : 0ULL;
    int my = __popcll(w0) + __popcll(w1);

    int scan = my;
    #pragma unroll
    for (int d = 1; d < 64; d <<= 1) {
        int v = __shfl_up(scan, d);
        if ((tid & 63) >= d) scan += v;
    }
    if ((tid & 63) == 63) wsum[tid >> 6] = scan;
    __syncthreads();
    int off = ((tid >= 64) ? wsum[0] : 0) + scan - my;
    int n = wsum[0] + wsum[1];

    int f0e = (chunk * CW + 2 * tid) * 64;
    unsigned long long m = w0;
    while (m) {
        int bit = __ffsll(m) - 1;
        if (off < LCAP) lf[off] = (f0e + bit) * OPAD;
        ++off; m &= m - 1;
    }
    m = w1; f0e += 64;
    while (m) {
        int bit = __ffsll(m) - 1;
        if (off < LCAP) lf[off] = (f0e + bit) * OPAD;
        ++off; m &= m - 1;
    }
    __syncthreads();
    if (n > LCAP) n = LCAP;

    if (tid * 4 < OPAD) {
        int o = tid * 4;
        const int* bq = QT + o;
        int a0 = 0, a1 = 0, a2 = 0, a3 = 0;
        int i = 0;
        for (; i + 8 <= n; i += 8) {
            int4 ia = *(const int4*)&lf[i];
            int4 ib = *(const int4*)&lf[i + 4];
            int e0 = __builtin_amdgcn_readfirstlane(ia.x);
            int e1 = __builtin_amdgcn_readfirstlane(ia.y);
            int e2 = __builtin_amdgcn_readfirstlane(ia.z);
            int e3 = __builtin_amdgcn_readfirstlane(ia.w);
            int e4 = __builtin_amdgcn_readfirstlane(ib.x);
            int e5 = __builtin_amdgcn_readfirstlane(ib.y);
            int e6 = __builtin_amdgcn_readfirstlane(ib.z);
            int e7 = __builtin_amdgcn_readfirstlane(ib.w);
            int4 q0 = *(const int4*)(bq + e0);
            int4 q1 = *(const int4*)(bq + e1);
            int4 q2 = *(const int4*)(bq + e2);
            int4 q3 = *(const int4*)(bq + e3);
            int4 q4 = *(const int4*)(bq + e4);
            int4 q5 = *(const int4*)(bq + e5);
            int4 q6 = *(const int4*)(bq + e6);
            int4 q7 = *(const int4*)(bq + e7);
            a0 += q0.x; a1 += q0.y; a2 += q0.z; a3 += q0.w;
            a0 += q1.x; a1 += q1.y; a2 += q1.z; a3 += q1.w;
            a0 += q2.x; a1 += q2.y; a2 += q2.z; a3 += q2.w;
            a0 += q3.x; a1 += q3.y; a2 += q3.z; a3 += q3.w;
            a0 += q4.x; a1 += q4.y; a2 += q4.z; a3 += q4.w;
            a0 += q5.x; a1 += q5.y; a2 += q5.z; a3 += q5.w;
            a0 += q6.x; a1 += q6.y; a2 += q6.z; a3 += q6.w;
            a0 += q7.x; a1 += q7.y; a2 += q7.z; a3 += q7.w;
        }
        for (; i < n; ++i) {
            int e = __builtin_amdgcn_readfirstlane(lf[i]);
            int4 q = *(const int4*)(bq + e);
            a0 += q.x; a1 += q.y; a2 += q.z; a3 += q.w;
        }
        int* zb = Z + ((size_t)chunk * NCOLS + col) * OPAD + o;
        *(int4*)zb = make_int4(a0, a1, a2, a3);
    }
}

template<int NCHUNK>
__global__ __launch_bounds__(320) void redpsp_kernel(
    const int* __restrict__ Z, double* __restrict__ U,
    int OPAD, int O, double scale)
{
    __shared__ double zs[16][304];
    __shared__ double eps[100];
    int og = blockIdx.x, b = blockIdx.y;
    int o0 = og * 16;
    int tid = threadIdx.x;

    if (tid < 100) {
        double td = (double)tid;
        eps[tid] = (td / 10.0) * exp(1.0 - td / 10.0);
    }
    int ol = tid & 15, tg = tid >> 4;
    #pragma unroll 3
    for (int tt = 0; tt < 15; ++tt) {
        int t = tg + tt * 20;
        const int* zp = Z + ((size_t)(b * T + t)) * OPAD + o0 + ol;
        long long s = 0;
        #pragma unroll
        for (int c = 0; c < NCHUNK; ++c)
            s += zp[(size_t)c * NCOLS * OPAD];
        zs[ol][t] = (double)s * scale;
    }
    __syncthreads();

    if (tid < T) {
        double sum[16];
        #pragma unroll
        for (int o = 0; o < 16; ++o) sum[o] = 0.0;
        int kmax = tid < 99 ? tid : 99;
        for (int k = 0; k <= kmax; ++k) {
            double e = eps[k];
            #pragma unroll
            for (int o = 0; o < 16; ++o)
                sum[o] = fma(e, zs[o][tid - k], sum[o]);
        }
        #pragma unroll
        for (int o = 0; o < 16; ++o) {
            int oo = o0 + o;
            if (oo < O) U[((size_t)b * O + oo) * T + tid] = sum[o];
        }
    }
}

// ---------------------------------------------------------------------------
// Spike LIF via exact finite-window recurrence, dbuf-staged (proven).
// ---------------------------------------------------------------------------
#define SPIKE_STAGE(BUF, T0, TIDX, NT)                                        \
    { int cl_ = T - (T0); if (cl_ > 64) cl_ = 64;                             \
      for (int idx = (TIDX); idx < 64 * 64; idx += (NT)) {                    \
        int r_ = idx >> 6, tl_ = idx & 63;                                    \
        int orow_ = w * 64 + r_; if (orow_ >= O) orow_ = O - 1;               \
        if (tl_ < cl_)                                                        \
            us[BUF][r_][tl_] = U[((size_t)b * O + orow_) * T + (T0) + tl_]; } }

__global__ __launch_bounds__(256) void spike_kernel(
    const double* __restrict__ U, unsigned long long* __restrict__ smask,
    float* __restrict__ sout, int O, int words)
{
    __shared__ double us[2][64][65];
    int w = blockIdx.x, b = blockIdx.y;
    int tid = threadIdx.x;
    int lane = tid & 63;
    int o = w * 64 + lane;
    bool active = (o < O);

    const double alpha = exp(-0.5);
    const double A31   = exp(-15.5);
    const double c0    = -10.0 * exp(1.0);

    SPIKE_STAGE(0, 0, tid, 256);
    __syncthreads();

    double E = 0.0, G = 0.0;
    unsigned hist = 0u;
    float* so = (sout && active) ? sout + ((size_t)b * O + o) * T : (float*)0;

    const int NCH = (T + 63) / 64;
    for (int c = 0; c < NCH; ++c) {
        int cur = c & 1;
        if (tid >= 64) {
            if (c + 1 < NCH) SPIKE_STAGE(cur ^ 1, (c + 1) * 64, tid - 64, 192);
        } else {
            int t0 = c * 64;
            int cl = T - t0; if (cl > 64) cl = 64;
            for (int tl = 0; tl < cl; ++tl) {
                double uval = active ? us[cur][lane][tl] : -1.0e300;
                double v = uval + c0 * G;
                bool sp = (v >= 10.0);
                unsigned long long bal = __ballot(sp);
                if (smask && lane == 0)
                    smask[((size_t)b * T + t0 + tl) * words + w] = bal;
                if (so) so[t0 + tl] = sp ? 1.0f : 0.0f;

                double sN  = sp ? 1.0 : 0.0;
                double s31 = ((hist >> 30) & 1u) ? 1.0 : 0.0;
                double Em  = E - A31 * s31;
                double Gm  = G - 31.0 * A31 * s31;
                G = alpha * (sN + Gm + Em);
                E = alpha * (sN + Em);
                hist = (hist << 1) | (sp ? 1u : 0u);
            }
        }
        __syncthreads();
    }
}

// ---------------------------------------------------------------------------
extern "C" void kernel_launch(void* const* d_in, const int* in_sizes, int n_in,
                              void* d_out, int out_size, void* d_ws, size_t ws_size,
                              hipStream_t stream)
{
    const float* x  = (const float*)d_in[0];
    const float* W1 = (const float*)d_in[1];
    const float* W2 = (const float*)d_in[2];
    const float* W3 = (const float*)d_in[3];
    float* out = (float*)d_out;

    const size_t sz_Aswz = (size_t)13 * 256 * 4 * 2048;      // 27.26 MB
    const size_t sz_Bswz = (size_t)8 * 256 * 10 * 2048;      // 41.94 MB
    const size_t sz_Pc   = (size_t)4 * PPLC * 8;             // 31.95 MB
    const size_t sz_u1   = (size_t)B * O1 * T * 8;           //  7.87 MB
    const size_t sz_Q2T  = (size_t)O1 * OP2 * 4;
    const size_t sz_Q3T  = (size_t)O2 * OP3 * 4;

    char* p = (char*)d_ws;
    char*      Aswz = p;                p += sz_Aswz;
    char*      Bswz = p;                p += sz_Bswz;
    long long* Pc   = (long long*)p;  char* pa = p;  p += sz_Pc;
    double*    u1   = (double*)p;       p += sz_u1;
    int*       Q2T  = (int*)p;          p += sz_Q2T;
    int*       Q3T  = (int*)p;          p += sz_Q3T;
    // Aliased into Pc's region (Pc dead after redpsp_mfma):
    int*                z2     = (int*)pa;                pa += (size_t)NCOLS * OP2 * 4;
    double*             u2     = (double*)pa;             pa += (size_t)B * O2 * T * 8;
    int*                z3     = (int*)pa;                pa += (size_t)NCOLS * OP3 * 4;
    double*             u3     = (double*)pa;             pa += (size_t)B * O3 * T * 8;
    unsigned long long* smask1 = (unsigned long long*)pa; pa += (size_t)NCOLS * W1M * 8;
    unsigned long long* smask2 = (unsigned long long*)pa; pa += (size_t)NCOLS * W2M * 8;

    const double sc26 = 1.0 / 67108864.0;

    // --- prep ---
    transpose_x_kernel<<<dim3(5, 256, B), dim3(256), 0, stream>>>(x, Bswz);
    quant_limb_kernel<<<dim3(4, 416), dim3(256), 0, stream>>>(W1, Aswz);
    quant_small_kernel<<<dim3((O1 * OP2 + 255) / 256), dim3(256), 0, stream>>>(
        W2, Q2T, O2, O1, OP2);
    quant_small_kernel<<<dim3((O2 * OP3 + 255) / 256), dim3(256), 0, stream>>>(
        W3, Q3T, O3, O2, OP3);

    // --- layer 1 (MFMA) ---
    mfma_gemm_kernel<<<dim3(16, 13, 4), dim3(256), 0, stream>>>(Aswz, Bswz, Pc);
    redpsp_mfma_kernel<<<dim3(26, B), dim3(320), 0, stream>>>(Pc, u1);
    spike_kernel<<<dim3(W1M, B), dim3(256), 0, stream>>>(u1, smask1, (float*)0, O1, W1M);

    // --- layer 2 (sparse) ---
    sparse_gemm_kernel<<<dim3(NCOLS), dim3(128), 0, stream>>>(
        Q2T, smask1, z2, OP2, W1M, W1M, 0);
    redpsp_kernel<1><<<dim3(OP2 / 16, B), dim3(320), 0, stream>>>(
        z2, u2, OP2, O2, sc26);
    spike_kernel<<<dim3(W2M, B), dim3(256), 0, stream>>>(u2, smask2, (float*)0, O2, W2M);

    // --- layer 3 (sparse) ---
    sparse_gemm_kernel<<<dim3(NCOLS), dim3(128), 0, stream>>>(
        Q3T, smask2, z3, OP3, W2M, W2M, 0);
    redpsp_kernel<1><<<dim3(OP3 / 16, B), dim3(320), 0, stream>>>(
        z3, u3, OP3, O3, sc26);
    spike_kernel<<<dim3(1, B), dim3(256), 0, stream>>>(u3, (unsigned long long*)0, out, O3, 0);
}

// Round 13
// 345.224 us; speedup vs baseline: 1.2617x; 1.0666x over previous
//
#include <hip/hip_runtime.h>

// ---------------------------------------------------------------------------
// SLAYER SNN on MI355X — layer 1 on i8 MATRIX CORES, exact integer limbs.
//   q[o,f] = rint(W1[o,f]*2^27) == l0 + 256 l1 + 65536 l2 + 2^24 l3 (signed
//   i8 limbs, exact). z*2^27 = sum_l 2^(8l) * (limb_l GEMM x), x in {0,1} i8,
//   v_mfma_i32_32x32x32_i8 (exact). M limb-interleaved (m=o*4+l): C/D quad q
//   holds all 4 limbs of o_loc=2q+h -> in-register combine to i64 (exact).
//   z BIT-IDENTICAL to the proven integer path.
// Round 13 (vs round 12's HBM-traffic-bound 125us, FETCH=152MB @1.5TB/s):
//  - B operand stored as BITS (5.24 MB vs 42 MB): Bbit[b][k16][col] u16;
//    fragments rebuilt in-register: byte i = bit i via
//    ((m>>4d)&15)*0x00204081 & 0x01010101  (identical bytes -> identical z).
//  - XCD co-location: 1D grid id = xcd + 8*(bh + 16*gq), g=mt*4+kc=xcd+8*gq
//    -> all 16 bh-sharers of an A-slice run on ONE XCD -> A fetched once.
// Layers 2/3 sparse path; spike via exact E,G recurrence (proven).
// ---------------------------------------------------------------------------

#define B   8
#define T   300
#define F0  16384
#define O1  410
#define O2  240
#define OP2 240
#define O3  10
#define OP3 16
#define W1M 7
#define W2M 4
#define NCOLS (B*T)      // 2400
#define LCAP 2048
#define PPLC ((size_t)416 * NCOLS)   // i64 elements per kc plane

typedef int  int32x4  __attribute__((ext_vector_type(4)));
typedef int  int32x16 __attribute__((ext_vector_type(16)));

// ---------------------------------------------------------------------------
// Bbit builder: x[b][f][t] f32 -> Bbit[b][k16][col] u16, bit j = x(k16*16+j, t).
// cols 300..319 left unwritten (stale) -> only affect discarded t>=300 outputs.
// ---------------------------------------------------------------------------
__global__ __launch_bounds__(256) void bitpack_x_kernel(
    const float* __restrict__ X, unsigned short* __restrict__ Bbit)
{
    __shared__ float tileT[64][65];    // [t-local][f-local]
    int tt = blockIdx.x;               // t-tile (0..4)
    int fb = blockIdx.y;               // 64-f block (0..255)
    int b  = blockIdx.z;
    int t0 = tt * 64, f0 = fb * 64;
    int tid = threadIdx.x;

    const float* Xb = X + ((size_t)b * F0 + f0) * T;
    int fl = tid >> 4;
    int tq = (tid & 15) * 4;
    #pragma unroll
    for (int i = 0; i < 4; ++i) {
        int fr = fl + i * 16;
        int t  = t0 + tq;
        float4 v = make_float4(0.f, 0.f, 0.f, 0.f);
        if (t < T) v = *(const float4*)(Xb + (size_t)fr * T + t);
        tileT[tq + 0][fr] = v.x;
        tileT[tq + 1][fr] = v.y;
        tileT[tq + 2][fr] = v.z;
        tileT[tq + 3][fr] = v.w;
    }
    __syncthreads();

    int k16l = tid >> 6;               // 0..3
    int tl   = tid & 63;
    unsigned m = 0u;
    #pragma unroll
    for (int j = 0; j < 16; ++j)
        m |= (tileT[tl][k16l * 16 + j] != 0.0f ? 1u : 0u) << j;
    int t = t0 + tl;
    if (t < T)
        Bbit[((size_t)b * 1024 + (f0 >> 4) + k16l) * 320 + t] = (unsigned short)m;
}

// ---------------------------------------------------------------------------
// Aswz builder: W1 -> 4 signed i8 limbs, limb-interleaved m = o*4+l (proven).
// ---------------------------------------------------------------------------
__global__ __launch_bounds__(256) void quant_limb_kernel(
    const float* __restrict__ W, char* __restrict__ Aswz)
{
    int o  = blockIdx.y;
    int f0 = (blockIdx.x * 256 + threadIdx.x) * 16;

    float w[16];
    if (o < O1) {
        #pragma unroll
        for (int e = 0; e < 16; e += 4)
            *(float4*)&w[e] = *(const float4*)(W + (size_t)o * F0 + f0 + e);
    } else {
        #pragma unroll
        for (int e = 0; e < 16; ++e) w[e] = 0.0f;
    }

    unsigned pk[4][4] = {{0,0,0,0},{0,0,0,0},{0,0,0,0},{0,0,0,0}};
    #pragma unroll
    for (int e = 0; e < 16; ++e) {
        int q = (int)__double2ll_rn((double)w[e] * 134217728.0);   // 2^27
        int l0 = (int)(signed char)(q & 255);  q = (q - l0) >> 8;
        int l1 = (int)(signed char)(q & 255);  q = (q - l1) >> 8;
        int l2 = (int)(signed char)(q & 255);  int l3 = (q - l2) >> 8;
        pk[0][e >> 2] |= (unsigned)(l0 & 255) << (8 * (e & 3));
        pk[1][e >> 2] |= (unsigned)(l1 & 255) << (8 * (e & 3));
        pk[2][e >> 2] |= (unsigned)(l2 & 255) << (8 * (e & 3));
        pk[3][e >> 2] |= (unsigned)(l3 & 255) << (8 * (e & 3));
    }

    int kit = f0 >> 6, ks = (f0 >> 5) & 1, hb = (f0 >> 4) & 1;
    #pragma unroll
    for (int l = 0; l < 4; ++l) {
        int m = o * 4 + l;
        int mt = m >> 7, r = m & 127, g = r >> 5, row = r & 31;
        int word = ks * 64 + row + 32 * hb;
        size_t addr = ((size_t)(mt * 256 + kit) * 4 + g) * 2048 + (size_t)word * 16;
        *(int32x4*)(Aswz + addr) =
            (int32x4){(int)pk[l][0], (int)pk[l][1], (int)pk[l][2], (int)pk[l][3]};
    }
}

__global__ __launch_bounds__(256) void quant_small_kernel(
    const float* __restrict__ W, int* __restrict__ QT, int O, int F, int OPAD)
{
    int idx = blockIdx.x * 256 + threadIdx.x;
    if (idx >= F * OPAD) return;
    int f = idx / OPAD, o = idx - f * OPAD;
    double v = (o < O) ? (double)W[(size_t)o * F + f] : 0.0;
    QT[idx] = (int)__double2ll_rn(v * 67108864.0);       // 2^26
}

// ---------------------------------------------------------------------------
// 16 bits -> 16 bytes (0/1): byte i = bit i. Exactly the Bswz byte pattern.
// ---------------------------------------------------------------------------
__device__ __forceinline__ int32x4 expand16(unsigned m)
{
    int32x4 r;
    r.x = (int)((((m      ) & 15u) * 0x00204081u) & 0x01010101u);
    r.y = (int)((((m >>  4) & 15u) * 0x00204081u) & 0x01010101u);
    r.z = (int)((((m >>  8) & 15u) * 0x00204081u) & 0x01010101u);
    r.w = (int)((((m >> 12) & 15u) * 0x00204081u) & 0x01010101u);
    return r;
}

// ---------------------------------------------------------------------------
// LDS-free i8 MFMA GEMM; B from bitmask; XCD-co-located A-slices.
// 1D grid 896: id = xcd + 8*(bh + 16*gq); g = xcd + 8*gq = mt*4 + kc (<52).
// Block = 4 waves (wm x wn); wn=0: ng0..2 (3 frags), wn=1: ng3..4 (2 frags).
// ---------------------------------------------------------------------------
__global__ __launch_bounds__(256) void mfma_gemm_kernel(
    const char* __restrict__ Aswz, const unsigned short* __restrict__ Bbit,
    long long* __restrict__ Pc)
{
    int id  = blockIdx.x;
    int xcd = id & 7, rr = id >> 3;
    int bh  = rr & 15, gq = rr >> 4;
    int g   = xcd + 8 * gq;
    if (g >= 52) return;
    int mt = g >> 2, kc = g & 3;
    int b = bh >> 1, half = bh & 1;

    int tid = threadIdx.x;
    int lane = tid & 63, wv = tid >> 6;
    int wm = wv >> 1, wn = wv & 1;
    int ng0 = wn * 3;
    int nfr = wn ? 2 : 3;              // wave-uniform

    const char* Ab = Aswz + ((size_t)(mt * 256 + kc * 64) * 4 + wm * 2) * 2048
                          + (size_t)lane * 16;
    const unsigned short* Bb = Bbit + (size_t)b * 1024 * 320;

    int hb = lane >> 5;
    int colf[3];
    #pragma unroll
    for (int fn = 0; fn < 3; ++fn)
        colf[fn] = (half * 5 + ng0 + fn) * 32 + (lane & 31);

    int32x16 acc[2][3];
    #pragma unroll
    for (int fm = 0; fm < 2; ++fm)
        #pragma unroll
        for (int fn = 0; fn < 3; ++fn)
            acc[fm][fn] = (int32x16){0,0,0,0,0,0,0,0,0,0,0,0,0,0,0,0};

    #pragma unroll 2
    for (int it = 0; it < 64; ++it) {
        int k16b = kc * 256 + it * 4 + hb;     // + ks*2
        int32x4 a[2][2], bv[3][2];
        #pragma unroll
        for (int fm = 0; fm < 2; ++fm)
            #pragma unroll
            for (int ks = 0; ks < 2; ++ks)
                a[fm][ks] = *(const int32x4*)(Ab + fm * 2048 + ks * 1024);
        #pragma unroll
        for (int fn = 0; fn < 3; ++fn)
            if (fn < nfr)
                #pragma unroll
                for (int ks = 0; ks < 2; ++ks) {
                    unsigned m = Bb[(size_t)(k16b + ks * 2) * 320 + colf[fn]];
                    bv[fn][ks] = expand16(m);
                }

        #pragma unroll
        for (int ks = 0; ks < 2; ++ks)
            #pragma unroll
            for (int fm = 0; fm < 2; ++fm)
                #pragma unroll
                for (int fn = 0; fn < 3; ++fn)
                    if (fn < nfr)
                        acc[fm][fn] = __builtin_amdgcn_mfma_i32_32x32x32_i8(
                            a[fm][ks], bv[fn][ks], acc[fm][fn], 0, 0, 0);

        Ab += 8192;        // 4 g-groups * 2048
    }

    // In-register limb combine -> i64 plane write.
    int col = lane & 31, h = lane >> 5;
    long long* Pk = Pc + (size_t)kc * PPLC + (size_t)b * T;
    #pragma unroll
    for (int fm = 0; fm < 2; ++fm) {
        #pragma unroll
        for (int fn = 0; fn < 3; ++fn) {
            if (fn >= nfr) continue;
            int t = (half * 5 + ng0 + fn) * 32 + col;
            if (t >= T) continue;
            int obase = mt * 32 + wm * 16 + fm * 8;
            #pragma unroll
            for (int q = 0; q < 4; ++q) {
                int o = obase + 2 * q + h;
                long long s = (long long)acc[fm][fn][4 * q]
                            + ((long long)acc[fm][fn][4 * q + 1] << 8)
                            + ((long long)acc[fm][fn][4 * q + 2] << 16)
                            + ((long long)acc[fm][fn][4 * q + 3] << 24);
                Pk[(size_t)o * NCOLS + t] = s;
            }
        }
    }
}

// ---------------------------------------------------------------------------
// Combine 4 kc planes (exact i64) + psp conv for layer 1.
// ---------------------------------------------------------------------------
__global__ __launch_bounds__(320) void redpsp_mfma_kernel(
    const long long* __restrict__ Pc, double* __restrict__ U)
{
    __shared__ double zs[16][304];
    __shared__ double eps[100];
    int og = blockIdx.x, b = blockIdx.y;
    int o0 = og * 16;
    int tid = threadIdx.x;
    const double sc27 = 1.0 / 134217728.0;

    if (tid < 100) {
        double td = (double)tid;
        eps[tid] = (td / 10.0) * exp(1.0 - td / 10.0);
    }
    if (tid < T) {
        size_t col = (size_t)b * T + tid;
        #pragma unroll 4
        for (int ol = 0; ol < 16; ++ol) {
            int o = o0 + ol;
            size_t idx = (size_t)o * NCOLS + col;
            long long s = Pc[idx] + Pc[PPLC + idx]
                        + Pc[2 * PPLC + idx] + Pc[3 * PPLC + idx];
            zs[ol][tid] = (double)s * sc27;
        }
    }
    __syncthreads();

    if (tid < T) {
        double sum[16];
        #pragma unroll
        for (int o = 0; o < 16; ++o) sum[o] = 0.0;
        int kmax = tid < 99 ? tid : 99;
        for (int k = 0; k <= kmax; ++k) {
            double e = eps[k];
            #pragma unroll
            for (int o = 0; o < 16; ++o)
                sum[o] = fma(e, zs[o][tid - k], sum[o]);
        }
        #pragma unroll
        for (int o = 0; o < 16; ++o) {
            int oo = o0 + o;
            if (oo < O1) U[((size_t)b * O1 + oo) * T + tid] = sum[o];
        }
    }
}

// ---------------------------------------------------------------------------
// Sparse integer GEMM for layers 2/3 (proven).
// ---------------------------------------------------------------------------
__global__ __launch_bounds__(128) void sparse_gemm_kernel(
    const int* __restrict__ QT, const unsigned long long* __restrict__ cmask,
    int* __restrict__ Z, int OPAD, int W, int CW, int cshift)
{
    __shared__ int lf[LCAP];
    __shared__ int wsum[2];

    int chunk = blockIdx.x & ((1 << cshift) - 1);
    int col   = blockIdx.x >> cshift;
    int tid   = threadIdx.x;

    int wbase = col * W + chunk * CW;
    unsigned long long w0 = (2 * tid     < CW) ? cmask[wbase + 2 * tid]     : 0ULL;
    unsigned long long w1 = (2 * tid + 1 < CW) ? cmask[wbase + 2 * tid + 1] : 0ULL;
    int my = __popcll(w0) + __popcll(w1);

    int scan = my;
    #pragma unroll
    for (int d = 1; d < 64; d <<= 1) {
        int v = __shfl_up(scan, d);
        if ((tid & 63) >= d) scan += v;
    }
    if ((tid & 63) == 63) wsum[tid >> 6] = scan;
    __syncthreads();
    int off = ((tid >= 64) ? wsum[0] : 0) + scan - my;
    int n = wsum[0] + wsum[1];

    int f0e = (chunk * CW + 2 * tid) * 64;
    unsigned long long m = w0;
    while (m) {
        int bit = __ffsll(m) - 1;
        if (off < LCAP) lf[off] = (f0e + bit) * OPAD;
        ++off; m &= m - 1;
    }
    m = w1; f0e += 64;
    while (m) {
        int bit = __ffsll(m) - 1;
        if (off < LCAP) lf[off] = (f0e + bit) * OPAD;
        ++off; m &= m - 1;
    }
    __syncthreads();
    if (n > LCAP) n = LCAP;

    if (tid * 4 < OPAD) {
        int o = tid * 4;
        const int* bq = QT + o;
        int a0 = 0, a1 = 0, a2 = 0, a3 = 0;
        int i = 0;
        for (; i + 8 <= n; i += 8) {
            int4 ia = *(const int4*)&lf[i];
            int4 ib = *(const int4*)&lf[i + 4];
            int e0 = __builtin_amdgcn_readfirstlane(ia.x);
            int e1 = __builtin_amdgcn_readfirstlane(ia.y);
            int e2 = __builtin_amdgcn_readfirstlane(ia.z);
            int e3 = __builtin_amdgcn_readfirstlane(ia.w);
            int e4 = __builtin_amdgcn_readfirstlane(ib.x);
            int e5 = __builtin_amdgcn_readfirstlane(ib.y);
            int e6 = __builtin_amdgcn_readfirstlane(ib.z);
            int e7 = __builtin_amdgcn_readfirstlane(ib.w);
            int4 q0 = *(const int4*)(bq + e0);
            int4 q1 = *(const int4*)(bq + e1);
            int4 q2 = *(const int4*)(bq + e2);
            int4 q3 = *(const int4*)(bq + e3);
            int4 q4 = *(const int4*)(bq + e4);
            int4 q5 = *(const int4*)(bq + e5);
            int4 q6 = *(const int4*)(bq + e6);
            int4 q7 = *(const int4*)(bq + e7);
            a0 += q0.x; a1 += q0.y; a2 += q0.z; a3 += q0.w;
            a0 += q1.x; a1 += q1.y; a2 += q1.z; a3 += q1.w;
            a0 += q2.x; a1 += q2.y; a2 += q2.z; a3 += q2.w;
            a0 += q3.x; a1 += q3.y; a2 += q3.z; a3 += q3.w;
            a0 += q4.x; a1 += q4.y; a2 += q4.z; a3 += q4.w;
            a0 += q5.x; a1 += q5.y; a2 += q5.z; a3 += q5.w;
            a0 += q6.x; a1 += q6.y; a2 += q6.z; a3 += q6.w;
            a0 += q7.x; a1 += q7.y; a2 += q7.z; a3 += q7.w;
        }
        for (; i < n; ++i) {
            int e = __builtin_amdgcn_readfirstlane(lf[i]);
            int4 q = *(const int4*)(bq + e);
            a0 += q.x; a1 += q.y; a2 += q.z; a3 += q.w;
        }
        int* zb = Z + ((size_t)chunk * NCOLS + col) * OPAD + o;
        *(int4*)zb = make_int4(a0, a1, a2, a3);
    }
}

template<int NCHUNK>
__global__ __launch_bounds__(320) void redpsp_kernel(
    const int* __restrict__ Z, double* __restrict__ U,
    int OPAD, int O, double scale)
{
    __shared__ double zs[16][304];
    __shared__ double eps[100];
    int og = blockIdx.x, b = blockIdx.y;
    int o0 = og * 16;
    int tid = threadIdx.x;

    if (tid < 100) {
        double td = (double)tid;
        eps[tid] = (td / 10.0) * exp(1.0 - td / 10.0);
    }
    int ol = tid & 15, tg = tid >> 4;
    #pragma unroll 3
    for (int tt = 0; tt < 15; ++tt) {
        int t = tg + tt * 20;
        const int* zp = Z + ((size_t)(b * T + t)) * OPAD + o0 + ol;
        long long s = 0;
        #pragma unroll
        for (int c = 0; c < NCHUNK; ++c)
            s += zp[(size_t)c * NCOLS * OPAD];
        zs[ol][t] = (double)s * scale;
    }
    __syncthreads();

    if (tid < T) {
        double sum[16];
        #pragma unroll
        for (int o = 0; o < 16; ++o) sum[o] = 0.0;
        int kmax = tid < 99 ? tid : 99;
        for (int k = 0; k <= kmax; ++k) {
            double e = eps[k];
            #pragma unroll
            for (int o = 0; o < 16; ++o)
                sum[o] = fma(e, zs[o][tid - k], sum[o]);
        }
        #pragma unroll
        for (int o = 0; o < 16; ++o) {
            int oo = o0 + o;
            if (oo < O) U[((size_t)b * O + oo) * T + tid] = sum[o];
        }
    }
}

// ---------------------------------------------------------------------------
// Spike LIF via exact finite-window recurrence, dbuf-staged (proven).
// ---------------------------------------------------------------------------
#define SPIKE_STAGE(BUF, T0, TIDX, NT)                                        \
    { int cl_ = T - (T0); if (cl_ > 64) cl_ = 64;                             \
      for (int idx = (TIDX); idx < 64 * 64; idx += (NT)) {                    \
        int r_ = idx >> 6, tl_ = idx & 63;                                    \
        int orow_ = w * 64 + r_; if (orow_ >= O) orow_ = O - 1;               \
        if (tl_ < cl_)                                                        \
            us[BUF][r_][tl_] = U[((size_t)b * O + orow_) * T + (T0) + tl_]; } }

__global__ __launch_bounds__(256) void spike_kernel(
    const double* __restrict__ U, unsigned long long* __restrict__ smask,
    float* __restrict__ sout, int O, int words)
{
    __shared__ double us[2][64][65];
    int w = blockIdx.x, b = blockIdx.y;
    int tid = threadIdx.x;
    int lane = tid & 63;
    int o = w * 64 + lane;
    bool active = (o < O);

    const double alpha = exp(-0.5);
    const double A31   = exp(-15.5);
    const double c0    = -10.0 * exp(1.0);

    SPIKE_STAGE(0, 0, tid, 256);
    __syncthreads();

    double E = 0.0, G = 0.0;
    unsigned hist = 0u;
    float* so = (sout && active) ? sout + ((size_t)b * O + o) * T : (float*)0;

    const int NCH = (T + 63) / 64;
    for (int c = 0; c < NCH; ++c) {
        int cur = c & 1;
        if (tid >= 64) {
            if (c + 1 < NCH) SPIKE_STAGE(cur ^ 1, (c + 1) * 64, tid - 64, 192);
        } else {
            int t0 = c * 64;
            int cl = T - t0; if (cl > 64) cl = 64;
            for (int tl = 0; tl < cl; ++tl) {
                double uval = active ? us[cur][lane][tl] : -1.0e300;
                double v = uval + c0 * G;
                bool sp = (v >= 10.0);
                unsigned long long bal = __ballot(sp);
                if (smask && lane == 0)
                    smask[((size_t)b * T + t0 + tl) * words + w] = bal;
                if (so) so[t0 + tl] = sp ? 1.0f : 0.0f;

                double sN  = sp ? 1.0 : 0.0;
                double s31 = ((hist >> 30) & 1u) ? 1.0 : 0.0;
                double Em  = E - A31 * s31;
                double Gm  = G - 31.0 * A31 * s31;
                G = alpha * (sN + Gm + Em);
                E = alpha * (sN + Em);
                hist = (hist << 1) | (sp ? 1u : 0u);
            }
        }
        __syncthreads();
    }
}

// ---------------------------------------------------------------------------
extern "C" void kernel_launch(void* const* d_in, const int* in_sizes, int n_in,
                              void* d_out, int out_size, void* d_ws, size_t ws_size,
                              hipStream_t stream)
{
    const float* x  = (const float*)d_in[0];
    const float* W1 = (const float*)d_in[1];
    const float* W2 = (const float*)d_in[2];
    const float* W3 = (const float*)d_in[3];
    float* out = (float*)d_out;

    const size_t sz_Aswz = (size_t)13 * 256 * 4 * 2048;      // 27.26 MB
    const size_t sz_Bbit = (size_t)B * 1024 * 320 * 2;       //  5.24 MB
    const size_t sz_Pc   = (size_t)4 * PPLC * 8;             // 31.95 MB
    const size_t sz_u1   = (size_t)B * O1 * T * 8;           //  7.87 MB
    const size_t sz_Q2T  = (size_t)O1 * OP2 * 4;
    const size_t sz_Q3T  = (size_t)O2 * OP3 * 4;

    char* p = (char*)d_ws;
    char*           Aswz = p;                 p += sz_Aswz;
    unsigned short* Bbit = (unsigned short*)p; p += sz_Bbit;
    long long*      Pc   = (long long*)p;  char* pa = p;  p += sz_Pc;
    double*         u1   = (double*)p;        p += sz_u1;
    int*            Q2T  = (int*)p;           p += sz_Q2T;
    int*            Q3T  = (int*)p;           p += sz_Q3T;
    // Aliased into Pc's region (Pc dead after redpsp_mfma):
    int*                z2     = (int*)pa;                pa += (size_t)NCOLS * OP2 * 4;
    double*             u2     = (double*)pa;             pa += (size_t)B * O2 * T * 8;
    int*                z3     = (int*)pa;                pa += (size_t)NCOLS * OP3 * 4;
    double*             u3     = (double*)pa;             pa += (size_t)B * O3 * T * 8;
    unsigned long long* smask1 = (unsigned long long*)pa; pa += (size_t)NCOLS * W1M * 8;
    unsigned long long* smask2 = (unsigned long long*)pa; pa += (size_t)NCOLS * W2M * 8;

    const double sc26 = 1.0 / 67108864.0;

    // --- prep ---
    bitpack_x_kernel<<<dim3(5, 256, B), dim3(256), 0, stream>>>(x, Bbit);
    quant_limb_kernel<<<dim3(4, 416), dim3(256), 0, stream>>>(W1, Aswz);
    quant_small_kernel<<<dim3((O1 * OP2 + 255) / 256), dim3(256), 0, stream>>>(
        W2, Q2T, O2, O1, OP2);
    quant_small_kernel<<<dim3((O2 * OP3 + 255) / 256), dim3(256), 0, stream>>>(
        W3, Q3T, O3, O2, OP3);

    // --- layer 1 (MFMA) ---
    mfma_gemm_kernel<<<dim3(896), dim3(256), 0, stream>>>(Aswz, Bbit, Pc);
    redpsp_mfma_kernel<<<dim3(26, B), dim3(320), 0, stream>>>(Pc, u1);
    spike_kernel<<<dim3(W1M, B), dim3(256), 0, stream>>>(u1, smask1, (float*)0, O1, W1M);

    // --- layer 2 (sparse) ---
    sparse_gemm_kernel<<<dim3(NCOLS), dim3(128), 0, stream>>>(
        Q2T, smask1, z2, OP2, W1M, W1M, 0);
    redpsp_kernel<1><<<dim3(OP2 / 16, B), dim3(320), 0, stream>>>(
        z2, u2, OP2, O2, sc26);
    spike_kernel<<<dim3(W2M, B), dim3(256), 0, stream>>>(u2, smask2, (float*)0, O2, W2M);

    // --- layer 3 (sparse) ---
    sparse_gemm_kernel<<<dim3(NCOLS), dim3(128), 0, stream>>>(
        Q3T, smask2, z3, OP3, W2M, W2M, 0);
    redpsp_kernel<1><<<dim3(OP3 / 16, B), dim3(320), 0, stream>>>(
        z3, u3, OP3, O3, sc26);
    spike_kernel<<<dim3(1, B), dim3(256), 0, stream>>>(u3, (unsigned long long*)0, out, O3, 0);
}

// Round 14
// 271.917 us; speedup vs baseline: 1.6018x; 1.2696x over previous
//
#include <hip/hip_runtime.h>

// ---------------------------------------------------------------------------
// SLAYER SNN on MI355X — layer 1 on i8 MATRIX CORES, exact integer limbs.
//   q[o,f] = rint(W1[o,f]*2^27) == l0 + 256 l1 + 65536 l2 + 2^24 l3 (signed
//   i8 limbs, exact). z*2^27 = sum_l 2^(8l) * (limb_l GEMM x), x in {0,1},
//   v_mfma_i32_32x32x32_i8 (exact). M limb-interleaved (m=o*4+l) -> limbs
//   combine in-register to i64. z BIT-IDENTICAL to the proven integer path.
// Round 14: (1) mfma_gemm software-pipelined (cur/nxt reg double-buffer;
// B bits fetched as one 8B dwordx2 per fragment from [b][it][col][4] layout);
// (2) spike LIF fused INTO the redpsp kernels (u stays in LDS; lanes 0-15
// run the proven E,G recurrence, emit u16 mask slices; no u buffers);
// (3) quant_small merged. 9 launches (was 13).
// ---------------------------------------------------------------------------

#define B   8
#define T   300
#define F0  16384
#define O1  410
#define O2  240
#define OP2 240
#define O3  10
#define OP3 16
#define W1M 7            // u64 words per layer-1 mask (28 u16 slots)
#define W2M 4            // u64 words per layer-2 mask (16 u16 slots)
#define NCOLS (B*T)      // 2400
#define LCAP 2048
#define PPLC ((size_t)416 * NCOLS)   // i64 elements per kc plane

typedef int  int32x4  __attribute__((ext_vector_type(4)));
typedef int  int32x16 __attribute__((ext_vector_type(16)));

// ---------------------------------------------------------------------------
// Bbit builder: x[b][f][t] -> Bbit[((b*256+it)*320+t)*4 + sub] u16,
// sub = k16 & 3, it = k16 >> 2, bit j of u16 = x(k16*16+j, t).
// t in [300,320) left unwritten (stale) -> only affects discarded outputs.
// ---------------------------------------------------------------------------
__global__ __launch_bounds__(256) void bitpack_x_kernel(
    const float* __restrict__ X, unsigned short* __restrict__ Bbit)
{
    __shared__ float tileT[64][65];    // [t-local][f-local]
    int tt = blockIdx.x;               // t-tile (0..4)
    int fb = blockIdx.y;               // 64-f block == it (0..255)
    int b  = blockIdx.z;
    int t0 = tt * 64, f0 = fb * 64;
    int tid = threadIdx.x;

    const float* Xb = X + ((size_t)b * F0 + f0) * T;
    int fl = tid >> 4;
    int tq = (tid & 15) * 4;
    #pragma unroll
    for (int i = 0; i < 4; ++i) {
        int fr = fl + i * 16;
        int t  = t0 + tq;
        float4 v = make_float4(0.f, 0.f, 0.f, 0.f);
        if (t < T) v = *(const float4*)(Xb + (size_t)fr * T + t);
        tileT[tq + 0][fr] = v.x;
        tileT[tq + 1][fr] = v.y;
        tileT[tq + 2][fr] = v.z;
        tileT[tq + 3][fr] = v.w;
    }
    __syncthreads();

    int sub = tid & 3;                 // k16 within it
    int tl  = tid >> 2;                // 0..63
    unsigned m = 0u;
    #pragma unroll
    for (int j = 0; j < 16; ++j)
        m |= (tileT[tl][sub * 16 + j] != 0.0f ? 1u : 0u) << j;
    int t = t0 + tl;
    if (t < T)
        Bbit[((size_t)(b * 256 + fb) * 320 + t) * 4 + sub] = (unsigned short)m;
}

// ---------------------------------------------------------------------------
// Aswz builder: W1 -> 4 signed i8 limbs, limb-interleaved m = o*4+l (proven).
// ---------------------------------------------------------------------------
__global__ __launch_bounds__(256) void quant_limb_kernel(
    const float* __restrict__ W, char* __restrict__ Aswz)
{
    int o  = blockIdx.y;
    int f0 = (blockIdx.x * 256 + threadIdx.x) * 16;

    float w[16];
    if (o < O1) {
        #pragma unroll
        for (int e = 0; e < 16; e += 4)
            *(float4*)&w[e] = *(const float4*)(W + (size_t)o * F0 + f0 + e);
    } else {
        #pragma unroll
        for (int e = 0; e < 16; ++e) w[e] = 0.0f;
    }

    unsigned pk[4][4] = {{0,0,0,0},{0,0,0,0},{0,0,0,0},{0,0,0,0}};
    #pragma unroll
    for (int e = 0; e < 16; ++e) {
        int q = (int)__double2ll_rn((double)w[e] * 134217728.0);   // 2^27
        int l0 = (int)(signed char)(q & 255);  q = (q - l0) >> 8;
        int l1 = (int)(signed char)(q & 255);  q = (q - l1) >> 8;
        int l2 = (int)(signed char)(q & 255);  int l3 = (q - l2) >> 8;
        pk[0][e >> 2] |= (unsigned)(l0 & 255) << (8 * (e & 3));
        pk[1][e >> 2] |= (unsigned)(l1 & 255) << (8 * (e & 3));
        pk[2][e >> 2] |= (unsigned)(l2 & 255) << (8 * (e & 3));
        pk[3][e >> 2] |= (unsigned)(l3 & 255) << (8 * (e & 3));
    }

    int kit = f0 >> 6, ks = (f0 >> 5) & 1, hb = (f0 >> 4) & 1;
    #pragma unroll
    for (int l = 0; l < 4; ++l) {
        int m = o * 4 + l;
        int mt = m >> 7, r = m & 127, g = r >> 5, row = r & 31;
        int word = ks * 64 + row + 32 * hb;
        size_t addr = ((size_t)(mt * 256 + kit) * 4 + g) * 2048 + (size_t)word * 16;
        *(int32x4*)(Aswz + addr) =
            (int32x4){(int)pk[l][0], (int)pk[l][1], (int)pk[l][2], (int)pk[l][3]};
    }
}

// Merged W2/W3 quantize+transpose (scale 2^26).
__global__ __launch_bounds__(256) void quant_small2_kernel(
    const float* __restrict__ W2, const float* __restrict__ W3,
    int* __restrict__ Q2T, int* __restrict__ Q3T)
{
    int idx = blockIdx.x * 256 + threadIdx.x;
    const int n1 = O1 * OP2;           // 98400
    const int n2 = O2 * OP3;           // 3840
    if (idx < n1) {
        int f = idx / OP2, o = idx - f * OP2;
        Q2T[idx] = (int)__double2ll_rn((double)W2[(size_t)o * O1 + f] * 67108864.0);
    } else if (idx < n1 + n2) {
        int j = idx - n1;
        int f = j / OP3, o = j - f * OP3;
        double v = (o < O3) ? (double)W3[(size_t)o * O2 + f] : 0.0;
        Q3T[j] = (int)__double2ll_rn(v * 67108864.0);
    }
}

// 16 bits -> 16 bytes (0/1): byte i = bit i.
__device__ __forceinline__ int32x4 expand16(unsigned m)
{
    int32x4 r;
    r.x = (int)((((m      ) & 15u) * 0x00204081u) & 0x01010101u);
    r.y = (int)((((m >>  4) & 15u) * 0x00204081u) & 0x01010101u);
    r.z = (int)((((m >>  8) & 15u) * 0x00204081u) & 0x01010101u);
    r.w = (int)((((m >> 12) & 15u) * 0x00204081u) & 0x01010101u);
    return r;
}

// ---------------------------------------------------------------------------
// LDS-free i8 MFMA GEMM, software-pipelined (cur/nxt reg double-buffer).
// 1D grid 896: id = xcd + 8*(bh + 16*gq); g = xcd+8*gq = mt*4+kc (<52)
// -> A-slice sharers co-locate on one XCD. 4 waves (wm x wn).
// ---------------------------------------------------------------------------
__global__ __launch_bounds__(256) void mfma_gemm_kernel(
    const char* __restrict__ Aswz, const unsigned short* __restrict__ Bbit,
    long long* __restrict__ Pc)
{
    int id  = blockIdx.x;
    int xcd = id & 7, rr = id >> 3;
    int bh  = rr & 15, gq = rr >> 4;
    int g   = xcd + 8 * gq;
    if (g >= 52) return;
    int mt = g >> 2, kc = g & 3;
    int b = bh >> 1, half = bh & 1;

    int tid = threadIdx.x;
    int lane = tid & 63, wv = tid >> 6;
    int wm = wv >> 1, wn = wv & 1;
    int ng0 = wn * 3;
    int nfr = wn ? 2 : 3;              // wave-uniform

    const char* Ab = Aswz + ((size_t)(mt * 256 + kc * 64) * 4 + wm * 2) * 2048
                          + (size_t)lane * 16;
    const char* Bb = (const char*)Bbit + (size_t)(b * 256 + kc * 64) * 320 * 8;
    int hb16 = (lane >> 5) * 16;

    const char* Bf[3];
    #pragma unroll
    for (int fn = 0; fn < 3; ++fn) {
        int colf = (half * 5 + ng0 + fn) * 32 + (lane & 31);
        Bf[fn] = Bb + (size_t)colf * 8;
    }

    int32x16 acc[2][3];
    #pragma unroll
    for (int fm = 0; fm < 2; ++fm)
        #pragma unroll
        for (int fn = 0; fn < 3; ++fn)
            acc[fm][fn] = (int32x16){0,0,0,0,0,0,0,0,0,0,0,0,0,0,0,0};

    int32x4 a_cur[2][2], a_nxt[2][2];
    uint2   r_cur[3],    r_nxt[3];

    // prologue: it = 0
    a_cur[0][0] = *(const int32x4*)(Ab);
    a_cur[0][1] = *(const int32x4*)(Ab + 1024);
    a_cur[1][0] = *(const int32x4*)(Ab + 2048);
    a_cur[1][1] = *(const int32x4*)(Ab + 3072);
    #pragma unroll
    for (int fn = 0; fn < 3; ++fn)
        if (fn < nfr) r_cur[fn] = *(const uint2*)(Bf[fn]);

    #pragma unroll 2
    for (int it = 0; it < 64; ++it) {
        int itn = (it < 63) ? it + 1 : it;         // wave-uniform guard
        const char* Abn = Ab + (size_t)itn * 8192;
        a_nxt[0][0] = *(const int32x4*)(Abn);
        a_nxt[0][1] = *(const int32x4*)(Abn + 1024);
        a_nxt[1][0] = *(const int32x4*)(Abn + 2048);
        a_nxt[1][1] = *(const int32x4*)(Abn + 3072);
        #pragma unroll
        for (int fn = 0; fn < 3; ++fn)
            if (fn < nfr)
                r_nxt[fn] = *(const uint2*)(Bf[fn] + (size_t)itn * 2560);

        #pragma unroll
        for (int ks = 0; ks < 2; ++ks)
            #pragma unroll
            for (int fn = 0; fn < 3; ++fn)
                if (fn < nfr) {
                    unsigned mraw = ks ? r_cur[fn].y : r_cur[fn].x;
                    int32x4 bvv = expand16((mraw >> hb16) & 0xFFFFu);
                    acc[0][fn] = __builtin_amdgcn_mfma_i32_32x32x32_i8(
                        a_cur[0][ks], bvv, acc[0][fn], 0, 0, 0);
                    acc[1][fn] = __builtin_amdgcn_mfma_i32_32x32x32_i8(
                        a_cur[1][ks], bvv, acc[1][fn], 0, 0, 0);
                }

        #pragma unroll
        for (int fm = 0; fm < 2; ++fm)
            #pragma unroll
            for (int ks = 0; ks < 2; ++ks)
                a_cur[fm][ks] = a_nxt[fm][ks];
        #pragma unroll
        for (int fn = 0; fn < 3; ++fn)
            if (fn < nfr) r_cur[fn] = r_nxt[fn];
    }

    // In-register limb combine -> i64 plane write.
    int col = lane & 31, h = lane >> 5;
    long long* Pk = Pc + (size_t)kc * PPLC + (size_t)b * T;
    #pragma unroll
    for (int fm = 0; fm < 2; ++fm) {
        #pragma unroll
        for (int fn = 0; fn < 3; ++fn) {
            if (fn >= nfr) continue;
            int t = (half * 5 + ng0 + fn) * 32 + col;
            if (t >= T) continue;
            int obase = mt * 32 + wm * 16 + fm * 8;
            #pragma unroll
            for (int q = 0; q < 4; ++q) {
                int o = obase + 2 * q + h;
                long long s = (long long)acc[fm][fn][4 * q]
                            + ((long long)acc[fm][fn][4 * q + 1] << 8)
                            + ((long long)acc[fm][fn][4 * q + 2] << 16)
                            + ((long long)acc[fm][fn][4 * q + 3] << 24);
                Pk[(size_t)o * NCOLS + t] = s;
            }
        }
    }
}

// ---------------------------------------------------------------------------
// Layer 1: combine 4 kc planes (exact i64) + psp conv + FUSED spike LIF.
// Lanes 0..15 of wave 0 run the proven E,G recurrence; l==0 stores the u16
// mask slice. og==25 zeroes trailing u16 slots 26,27 (bits 416..447).
// ---------------------------------------------------------------------------
__global__ __launch_bounds__(320) void redpsp1_kernel(
    const long long* __restrict__ Pc, unsigned short* __restrict__ smask)
{
    __shared__ double zs[16][304];
    __shared__ double us[16][304];
    __shared__ double eps[100];
    int og = blockIdx.x, b = blockIdx.y;
    int o0 = og * 16;
    int tid = threadIdx.x;
    const double sc27 = 1.0 / 134217728.0;

    if (tid < 100) {
        double td = (double)tid;
        eps[tid] = (td / 10.0) * exp(1.0 - td / 10.0);
    }
    if (tid < T) {
        size_t col = (size_t)b * T + tid;
        #pragma unroll 4
        for (int ol = 0; ol < 16; ++ol) {
            int o = o0 + ol;
            size_t idx = (size_t)o * NCOLS + col;
            long long s = Pc[idx] + Pc[PPLC + idx]
                        + Pc[2 * PPLC + idx] + Pc[3 * PPLC + idx];
            zs[ol][tid] = (double)s * sc27;
        }
    }
    __syncthreads();

    if (tid < T) {
        double sum[16];
        #pragma unroll
        for (int o = 0; o < 16; ++o) sum[o] = 0.0;
        int kmax = tid < 99 ? tid : 99;
        for (int k = 0; k <= kmax; ++k) {
            double e = eps[k];
            #pragma unroll
            for (int o = 0; o < 16; ++o)
                sum[o] = fma(e, zs[o][tid - k], sum[o]);
        }
        #pragma unroll
        for (int o = 0; o < 16; ++o) us[o][tid] = sum[o];
    }
    if (og == 25 && tid < T) {     // zero mask bits 416..447
        size_t col = (size_t)b * T + tid;
        *(unsigned*)((char*)smask + (col * 28 + 26) * 2) = 0u;
    }
    __syncthreads();

    if (tid < 64) {
        int l = tid;
        bool act = (l < 16) && (o0 + l < O1);
        const double alpha = exp(-0.5);
        const double A31   = exp(-15.5);
        const double c0    = -10.0 * exp(1.0);
        double E = 0.0, G = 0.0;
        unsigned hist = 0u;
        for (int t = 0; t < T; ++t) {
            double uval = act ? us[l][t] : -1.0e300;
            double v = uval + c0 * G;
            bool sp = (v >= 10.0);
            unsigned long long bal = __ballot(sp);
            if (l == 0)
                smask[((size_t)b * T + t) * 28 + og] =
                    (unsigned short)(bal & 0xFFFFu);
            double sN  = sp ? 1.0 : 0.0;
            double s31 = ((hist >> 30) & 1u) ? 1.0 : 0.0;
            double Em  = E - A31 * s31;
            double Gm  = G - 31.0 * A31 * s31;
            G = alpha * (sN + Gm + Em);
            E = alpha * (sN + Em);
            hist = (hist << 1) | (sp ? 1u : 0u);
        }
    }
}

// ---------------------------------------------------------------------------
// Layers 2/3: reduce (i32 z, scale) + psp conv + fused spike.
// SLOTS>0: write u16 mask slices (last og zeroes trailing slots).
// OUT: write f32 spikes to sout.
// ---------------------------------------------------------------------------
template<int OPAD_, int O_, int SLOTS, int NOG, bool OUT>
__global__ __launch_bounds__(320) void redpsp23_kernel(
    const int* __restrict__ Z, unsigned short* __restrict__ smask,
    float* __restrict__ sout, double scale)
{
    __shared__ double zs[16][304];
    __shared__ double us[16][304];
    __shared__ double eps[100];
    int og = blockIdx.x, b = blockIdx.y;
    int o0 = og * 16;
    int tid = threadIdx.x;

    if (tid < 100) {
        double td = (double)tid;
        eps[tid] = (td / 10.0) * exp(1.0 - td / 10.0);
    }
    if (tid < T) {
        size_t col = (size_t)b * T + tid;
        #pragma unroll 4
        for (int ol = 0; ol < 16; ++ol) {
            int o = o0 + ol;
            double zv = (o < OPAD_) ? (double)Z[col * OPAD_ + o] * scale : 0.0;
            zs[ol][tid] = zv;
        }
    }
    __syncthreads();

    if (tid < T) {
        double sum[16];
        #pragma unroll
        for (int o = 0; o < 16; ++o) sum[o] = 0.0;
        int kmax = tid < 99 ? tid : 99;
        for (int k = 0; k <= kmax; ++k) {
            double e = eps[k];
            #pragma unroll
            for (int o = 0; o < 16; ++o)
                sum[o] = fma(e, zs[o][tid - k], sum[o]);
        }
        #pragma unroll
        for (int o = 0; o < 16; ++o) us[o][tid] = sum[o];
    }
    if (SLOTS > NOG && og == NOG - 1 && tid < T) {
        size_t col = (size_t)b * T + tid;
        #pragma unroll
        for (int s = NOG; s < SLOTS; ++s)
            smask[col * SLOTS + s] = 0;
    }
    __syncthreads();

    if (tid < 64) {
        int l = tid;
        bool act = (l < 16) && (o0 + l < O_);
        const double alpha = exp(-0.5);
        const double A31   = exp(-15.5);
        const double c0    = -10.0 * exp(1.0);
        double E = 0.0, G = 0.0;
        unsigned hist = 0u;
        for (int t = 0; t < T; ++t) {
            double uval = act ? us[l][t] : -1.0e300;
            double v = uval + c0 * G;
            bool sp = (v >= 10.0);
            unsigned long long bal = __ballot(sp);
            if (SLOTS > 0 && l == 0)
                smask[((size_t)b * T + t) * SLOTS + og] =
                    (unsigned short)(bal & 0xFFFFu);
            if (OUT && act)
                sout[((size_t)b * O_ + o0 + l) * T + t] = sp ? 1.0f : 0.0f;
            double sN  = sp ? 1.0 : 0.0;
            double s31 = ((hist >> 30) & 1u) ? 1.0 : 0.0;
            double Em  = E - A31 * s31;
            double Gm  = G - 31.0 * A31 * s31;
            G = alpha * (sN + Gm + Em);
            E = alpha * (sN + Em);
            hist = (hist << 1) | (sp ? 1u : 0u);
        }
    }
}

// ---------------------------------------------------------------------------
// Sparse integer GEMM for layers 2/3 (proven; masks read as u64 words).
// ---------------------------------------------------------------------------
__global__ __launch_bounds__(128) void sparse_gemm_kernel(
    const int* __restrict__ QT, const unsigned long long* __restrict__ cmask,
    int* __restrict__ Z, int OPAD, int W, int CW, int cshift)
{
    __shared__ int lf[LCAP];
    __shared__ int wsum[2];

    int chunk = blockIdx.x & ((1 << cshift) - 1);
    int col   = blockIdx.x >> cshift;
    int tid   = threadIdx.x;

    int wbase = col * W + chunk * CW;
    unsigned long long w0 = (2 * tid     < CW) ? cmask[wbase + 2 * tid]     : 0ULL;
    unsigned long long w1 = (2 * tid + 1 < CW) ? cmask[wbase + 2 * tid + 1] : 0ULL;
    int my = __popcll(w0) + __popcll(w1);

    int scan = my;
    #pragma unroll
    for (int d = 1; d < 64; d <<= 1) {
        int v = __shfl_up(scan, d);
        if ((tid & 63) >= d) scan += v;
    }
    if ((tid & 63) == 63) wsum[tid >> 6] = scan;
    __syncthreads();
    int off = ((tid >= 64) ? wsum[0] : 0) + scan - my;
    int n = wsum[0] + wsum[1];

    int f0e = (chunk * CW + 2 * tid) * 64;
    unsigned long long m = w0;
    while (m) {
        int bit = __ffsll(m) - 1;
        if (off < LCAP) lf[off] = (f0e + bit) * OPAD;
        ++off; m &= m - 1;
    }
    m = w1; f0e += 64;
    while (m) {
        int bit = __ffsll(m) - 1;
        if (off < LCAP) lf[off] = (f0e + bit) * OPAD;
        ++off; m &= m - 1;
    }
    __syncthreads();
    if (n > LCAP) n = LCAP;

    if (tid * 4 < OPAD) {
        int o = tid * 4;
        const int* bq = QT + o;
        int a0 = 0, a1 = 0, a2 = 0, a3 = 0;
        int i = 0;
        for (; i + 8 <= n; i += 8) {
            int4 ia = *(const int4*)&lf[i];
            int4 ib = *(const int4*)&lf[i + 4];
            int e0 = __builtin_amdgcn_readfirstlane(ia.x);
            int e1 = __builtin_amdgcn_readfirstlane(ia.y);
            int e2 = __builtin_amdgcn_readfirstlane(ia.z);
            int e3 = __builtin_amdgcn_readfirstlane(ia.w);
            int e4 = __builtin_amdgcn_readfirstlane(ib.x);
            int e5 = __builtin_amdgcn_readfirstlane(ib.y);
            int e6 = __builtin_amdgcn_readfirstlane(ib.z);
            int e7 = __builtin_amdgcn_readfirstlane(ib.w);
            int4 q0 = *(const int4*)(bq + e0);
            int4 q1 = *(const int4*)(bq + e1);
            int4 q2 = *(const int4*)(bq + e2);
            int4 q3 = *(const int4*)(bq + e3);
            int4 q4 = *(const int4*)(bq + e4);
            int4 q5 = *(const int4*)(bq + e5);
            int4 q6 = *(const int4*)(bq + e6);
            int4 q7 = *(const int4*)(bq + e7);
            a0 += q0.x; a1 += q0.y; a2 += q0.z; a3 += q0.w;
            a0 += q1.x; a1 += q1.y; a2 += q1.z; a3 += q1.w;
            a0 += q2.x; a1 += q2.y; a2 += q2.z; a3 += q2.w;
            a0 += q3.x; a1 += q3.y; a2 += q3.z; a3 += q3.w;
            a0 += q4.x; a1 += q4.y; a2 += q4.z; a3 += q4.w;
            a0 += q5.x; a1 += q5.y; a2 += q5.z; a3 += q5.w;
            a0 += q6.x; a1 += q6.y; a2 += q6.z; a3 += q6.w;
            a0 += q7.x; a1 += q7.y; a2 += q7.z; a3 += q7.w;
        }
        for (; i < n; ++i) {
            int e = __builtin_amdgcn_readfirstlane(lf[i]);
            int4 q = *(const int4*)(bq + e);
            a0 += q.x; a1 += q.y; a2 += q.z; a3 += q.w;
        }
        int* zb = Z + ((size_t)chunk * NCOLS + col) * OPAD + o;
        *(int4*)zb = make_int4(a0, a1, a2, a3);
    }
}

// ---------------------------------------------------------------------------
extern "C" void kernel_launch(void* const* d_in, const int* in_sizes, int n_in,
                              void* d_out, int out_size, void* d_ws, size_t ws_size,
                              hipStream_t stream)
{
    const float* x  = (const float*)d_in[0];
    const float* W1 = (const float*)d_in[1];
    const float* W2 = (const float*)d_in[2];
    const float* W3 = (const float*)d_in[3];
    float* out = (float*)d_out;

    const size_t sz_Aswz   = (size_t)13 * 256 * 4 * 2048;      // 27.26 MB
    const size_t sz_Bbit   = (size_t)B * 256 * 320 * 4 * 2;    //  5.24 MB
    const size_t sz_Pc     = (size_t)4 * PPLC * 8;             // 31.95 MB
    const size_t sz_Q2T    = (size_t)O1 * OP2 * 4;
    const size_t sz_Q3T    = (size_t)O2 * OP3 * 4;
    const size_t sz_smask1 = (size_t)NCOLS * 28 * 2;           // 134 KB
    const size_t sz_smask2 = (size_t)NCOLS * 16 * 2;           //  77 KB

    char* p = (char*)d_ws;
    char*           Aswz   = p;                  p += sz_Aswz;
    unsigned short* Bbit   = (unsigned short*)p; p += sz_Bbit;
    long long*      Pc     = (long long*)p;  char* pa = p;  p += sz_Pc;
    int*            Q2T    = (int*)p;            p += sz_Q2T;
    int*            Q3T    = (int*)p;            p += sz_Q3T;
    unsigned short* smask1 = (unsigned short*)p; p += sz_smask1;
    unsigned short* smask2 = (unsigned short*)p; p += sz_smask2;
    // z2/z3 alias Pc's region (Pc dead after redpsp1):
    int* z2 = (int*)pa;                          pa += (size_t)NCOLS * OP2 * 4;
    int* z3 = (int*)pa;                          pa += (size_t)NCOLS * OP3 * 4;

    const double sc26 = 1.0 / 67108864.0;

    // --- prep ---
    bitpack_x_kernel<<<dim3(5, 256, B), dim3(256), 0, stream>>>(x, Bbit);
    quant_limb_kernel<<<dim3(4, 416), dim3(256), 0, stream>>>(W1, Aswz);
    quant_small2_kernel<<<dim3((O1 * OP2 + O2 * OP3 + 255) / 256), dim3(256), 0, stream>>>(
        W2, W3, Q2T, Q3T);

    // --- layer 1 (MFMA + fused psp/spike) ---
    mfma_gemm_kernel<<<dim3(896), dim3(256), 0, stream>>>(Aswz, Bbit, Pc);
    redpsp1_kernel<<<dim3(26, B), dim3(320), 0, stream>>>(Pc, smask1);

    // --- layer 2 ---
    sparse_gemm_kernel<<<dim3(NCOLS), dim3(128), 0, stream>>>(
        Q2T, (const unsigned long long*)smask1, z2, OP2, W1M, W1M, 0);
    redpsp23_kernel<OP2, O2, 16, 15, false><<<dim3(15, B), dim3(320), 0, stream>>>(
        z2, smask2, (float*)0, sc26);

    // --- layer 3 ---
    sparse_gemm_kernel<<<dim3(NCOLS), dim3(128), 0, stream>>>(
        Q3T, (const unsigned long long*)smask2, z3, OP3, W2M, W2M, 0);
    redpsp23_kernel<OP3, O3, 0, 1, true><<<dim3(1, B), dim3(320), 0, stream>>>(
        z3, (unsigned short*)0, out, sc26);
}

// Round 15
// 259.899 us; speedup vs baseline: 1.6759x; 1.0462x over previous
//
#include <hip/hip_runtime.h>

// ---------------------------------------------------------------------------
// SLAYER SNN on MI355X — layer 1 on i8 MATRIX CORES, exact integer limbs.
//   q[o,f] = rint(W1[o,f]*2^27) == l0 + 256 l1 + 65536 l2 + 2^24 l3 (signed
//   i8 limbs, exact). z*2^27 = sum_l 2^(8l) * (limb_l GEMM x), x in {0,1},
//   v_mfma_i32_32x32x32_i8 (exact). M limb-interleaved (m=o*4+l) -> limbs
//   combine in-register; per-kc partial fits i32 at 22 sigma (proven margin
//   class from rounds 7-9); wrapping-u32 combine is exact since |s| < 2^31.
//   8 i32 kc-planes sum exactly in i64 in redpsp1 -> z integer-identical.
// Round 15: (1) software pipeline WITHOUT register copies (2-stage manual
// rotation); (2) kc=8 -> 1664 blocks = 6.5 blocks/CU = 26 waves/CU for
// latency hiding (Pc stays 32 MB via i32 planes); (3) prep kernels fused.
// Layers 2/3 sparse path + fused redpsp/spike (proven).
// ---------------------------------------------------------------------------

#define B   8
#define T   300
#define F0  16384
#define O1  410
#define O2  240
#define OP2 240
#define O3  10
#define OP3 16
#define W1M 7             // u64 words per layer-1 mask (28 u16 slots)
#define W2M 4             // u64 words per layer-2 mask (16 u16 slots)
#define NCOLS (B*T)       // 2400
#define LCAP 2048
#define PPLC32 ((size_t)416 * NCOLS)   // i32 elements per kc plane

typedef int  int32x4  __attribute__((ext_vector_type(4)));
typedef int  int32x16 __attribute__((ext_vector_type(16)));

// 16 bits -> 16 bytes (0/1): byte i = bit i. Exactly the fragment pattern.
__device__ __forceinline__ int32x4 expand16(unsigned m)
{
    int32x4 r;
    r.x = (int)((((m      ) & 15u) * 0x00204081u) & 0x01010101u);
    r.y = (int)((((m >>  4) & 15u) * 0x00204081u) & 0x01010101u);
    r.z = (int)((((m >>  8) & 15u) * 0x00204081u) & 0x01010101u);
    r.w = (int)((((m >> 12) & 15u) * 0x00204081u) & 0x01010101u);
    return r;
}

// ---------------------------------------------------------------------------
// Fused prep: [0,10240) bitpack x; [10240,11904) quant W1 limbs;
// [11904,12304) quant W2/W3.
// Bbit[((b*256+it)*320+t)*4 + sub] u16; bit j = x(it*64+sub*16+j, t).
// ---------------------------------------------------------------------------
__global__ __launch_bounds__(256) void prep_kernel(
    const float* __restrict__ X,  const float* __restrict__ W1,
    const float* __restrict__ W2, const float* __restrict__ W3,
    unsigned short* __restrict__ Bbit, char* __restrict__ Aswz,
    int* __restrict__ Q2T, int* __restrict__ Q3T)
{
    __shared__ float tileT[64][65];
    int bid = blockIdx.x;
    int tid = threadIdx.x;

    if (bid < 10240) {                           // ---- bitpack x ----
        int tt = bid % 5, fb = (bid / 5) % 256, b = bid / 1280;
        int t0 = tt * 64, f0 = fb * 64;
        const float* Xb = X + ((size_t)b * F0 + f0) * T;
        int fl = tid >> 4;
        int tq = (tid & 15) * 4;
        #pragma unroll
        for (int i = 0; i < 4; ++i) {
            int fr = fl + i * 16;
            int t  = t0 + tq;
            float4 v = make_float4(0.f, 0.f, 0.f, 0.f);
            if (t < T) v = *(const float4*)(Xb + (size_t)fr * T + t);
            tileT[tq + 0][fr] = v.x;
            tileT[tq + 1][fr] = v.y;
            tileT[tq + 2][fr] = v.z;
            tileT[tq + 3][fr] = v.w;
        }
        __syncthreads();
        int sub = tid & 3;
        int tl  = tid >> 2;
        unsigned m = 0u;
        #pragma unroll
        for (int j = 0; j < 16; ++j)
            m |= (tileT[tl][sub * 16 + j] != 0.0f ? 1u : 0u) << j;
        int t = t0 + tl;
        if (t < T)
            Bbit[((size_t)(b * 256 + fb) * 320 + t) * 4 + sub] = (unsigned short)m;

    } else if (bid < 11904) {                    // ---- quant W1 limbs ----
        int j = bid - 10240;                     // 0..1663
        int o  = j >> 2;
        int f0 = ((j & 3) * 256 + tid) * 16;

        float w[16];
        if (o < O1) {
            #pragma unroll
            for (int e = 0; e < 16; e += 4)
                *(float4*)&w[e] = *(const float4*)(W1 + (size_t)o * F0 + f0 + e);
        } else {
            #pragma unroll
            for (int e = 0; e < 16; ++e) w[e] = 0.0f;
        }

        unsigned pk[4][4] = {{0,0,0,0},{0,0,0,0},{0,0,0,0},{0,0,0,0}};
        #pragma unroll
        for (int e = 0; e < 16; ++e) {
            int q = (int)__double2ll_rn((double)w[e] * 134217728.0);   // 2^27
            int l0 = (int)(signed char)(q & 255);  q = (q - l0) >> 8;
            int l1 = (int)(signed char)(q & 255);  q = (q - l1) >> 8;
            int l2 = (int)(signed char)(q & 255);  int l3 = (q - l2) >> 8;
            pk[0][e >> 2] |= (unsigned)(l0 & 255) << (8 * (e & 3));
            pk[1][e >> 2] |= (unsigned)(l1 & 255) << (8 * (e & 3));
            pk[2][e >> 2] |= (unsigned)(l2 & 255) << (8 * (e & 3));
            pk[3][e >> 2] |= (unsigned)(l3 & 255) << (8 * (e & 3));
        }

        int kit = f0 >> 6, ks = (f0 >> 5) & 1, hb = (f0 >> 4) & 1;
        #pragma unroll
        for (int l = 0; l < 4; ++l) {
            int m = o * 4 + l;
            int mt = m >> 7, r = m & 127, g = r >> 5, row = r & 31;
            int word = ks * 64 + row + 32 * hb;
            size_t addr = ((size_t)(mt * 256 + kit) * 4 + g) * 2048 + (size_t)word * 16;
            *(int32x4*)(Aswz + addr) =
                (int32x4){(int)pk[l][0], (int)pk[l][1], (int)pk[l][2], (int)pk[l][3]};
        }

    } else {                                     // ---- quant W2/W3 ----
        int idx = (bid - 11904) * 256 + tid;
        const int n1 = O1 * OP2;                 // 98400
        const int n2 = O2 * OP3;                 // 3840
        if (idx < n1) {
            int f = idx / OP2, o = idx - f * OP2;
            Q2T[idx] = (int)__double2ll_rn((double)W2[(size_t)o * O1 + f] * 67108864.0);
        } else if (idx < n1 + n2) {
            int j = idx - n1;
            int f = j / OP3, o = j - f * OP3;
            double v = (o < O3) ? (double)W3[(size_t)o * O2 + f] : 0.0;
            Q3T[j] = (int)__double2ll_rn(v * 67108864.0);
        }
    }
}

// ---------------------------------------------------------------------------
// LDS-free i8 MFMA GEMM, copy-free 2-stage pipeline, kc=8.
// 1D grid 1664: id = xcd + 8*(bh + 16*gq); g = xcd+8*gq (<104); mt=g>>3,
// kc=g&7 -> 16 bh-sharers of each A-slice co-locate on one XCD.
// Block = 4 waves (wm x wn); wn=0: 3 n-frags, wn=1: 2. 32 K-iters.
// ---------------------------------------------------------------------------
__global__ __launch_bounds__(256) void mfma_gemm_kernel(
    const char* __restrict__ Aswz, const unsigned short* __restrict__ Bbit,
    int* __restrict__ Pc)
{
    int id  = blockIdx.x;
    int xcd = id & 7, rr = id >> 3;
    int bh  = rr & 15, gq = rr >> 4;
    int g   = xcd + 8 * gq;                      // 0..103, exact
    int mt = g >> 3, kc = g & 7;
    int b = bh >> 1, half = bh & 1;

    int tid = threadIdx.x;
    int lane = tid & 63, wv = tid >> 6;
    int wm = wv >> 1, wn = wv & 1;
    int ng0 = wn * 3;
    int nfr = wn ? 2 : 3;                        // wave-uniform

    const char* Ab = Aswz + ((size_t)(mt * 256 + kc * 32) * 4 + wm * 2) * 2048
                          + (size_t)lane * 16;
    const char* Bb = (const char*)Bbit + (size_t)(b * 256 + kc * 32) * 320 * 8;
    int hb16 = (lane >> 5) * 16;

    const char* Bf[3];
    #pragma unroll
    for (int fn = 0; fn < 3; ++fn) {
        int colf = (half * 5 + ng0 + fn) * 32 + (lane & 31);
        Bf[fn] = Bb + (size_t)colf * 8;
    }

    int32x16 acc[2][3];
    #pragma unroll
    for (int fm = 0; fm < 2; ++fm)
        #pragma unroll
        for (int fn = 0; fn < 3; ++fn)
            acc[fm][fn] = (int32x16){0,0,0,0,0,0,0,0,0,0,0,0,0,0,0,0};

    int32x4 aA[2][2], aB[2][2];
    uint2   rA[3],    rB[3];

#define LOAD_STAGE(AR, RR, ITN)                                               \
    { const char* Abn_ = Ab + (size_t)(ITN) * 8192;                           \
      AR[0][0] = *(const int32x4*)(Abn_);                                     \
      AR[0][1] = *(const int32x4*)(Abn_ + 1024);                              \
      AR[1][0] = *(const int32x4*)(Abn_ + 2048);                              \
      AR[1][1] = *(const int32x4*)(Abn_ + 3072);                              \
      _Pragma("unroll")                                                       \
      for (int fn_ = 0; fn_ < 3; ++fn_)                                       \
          if (fn_ < nfr)                                                      \
              RR[fn_] = *(const uint2*)(Bf[fn_] + (size_t)(ITN) * 2560); }

#define COMPUTE_STAGE(AR, RR)                                                 \
    { _Pragma("unroll")                                                       \
      for (int ks_ = 0; ks_ < 2; ++ks_)                                       \
          _Pragma("unroll")                                                   \
          for (int fn_ = 0; fn_ < 3; ++fn_)                                   \
              if (fn_ < nfr) {                                                \
                  unsigned mraw_ = ks_ ? RR[fn_].y : RR[fn_].x;               \
                  int32x4 bvv_ = expand16((mraw_ >> hb16) & 0xFFFFu);         \
                  acc[0][fn_] = __builtin_amdgcn_mfma_i32_32x32x32_i8(        \
                      AR[0][ks_], bvv_, acc[0][fn_], 0, 0, 0);                \
                  acc[1][fn_] = __builtin_amdgcn_mfma_i32_32x32x32_i8(        \
                      AR[1][ks_], bvv_, acc[1][fn_], 0, 0, 0);                \
              } }

    LOAD_STAGE(aA, rA, 0);
    for (int it = 0; it < 32; it += 2) {
        LOAD_STAGE(aB, rB, it + 1);              // it+1 <= 31 always
        COMPUTE_STAGE(aA, rA);
        int itn2 = (it + 2 < 32) ? it + 2 : 31;  // last prefetch harmless
        LOAD_STAGE(aA, rA, itn2);
        COMPUTE_STAGE(aB, rB);
    }
#undef LOAD_STAGE
#undef COMPUTE_STAGE

    // In-register limb combine in wrapping u32 (exact: |s| < 2^31) -> i32.
    int col = lane & 31, h = lane >> 5;
    int* Pk = Pc + (size_t)kc * PPLC32 + (size_t)b * T;
    #pragma unroll
    for (int fm = 0; fm < 2; ++fm) {
        #pragma unroll
        for (int fn = 0; fn < 3; ++fn) {
            if (fn >= nfr) continue;
            int t = (half * 5 + ng0 + fn) * 32 + col;
            if (t >= T) continue;
            int obase = mt * 32 + wm * 16 + fm * 8;
            #pragma unroll
            for (int q = 0; q < 4; ++q) {
                int o = obase + 2 * q + h;
                unsigned s = (unsigned)acc[fm][fn][4 * q]
                           + ((unsigned)acc[fm][fn][4 * q + 1] << 8)
                           + ((unsigned)acc[fm][fn][4 * q + 2] << 16)
                           + ((unsigned)acc[fm][fn][4 * q + 3] << 24);
                Pk[(size_t)o * NCOLS + t] = (int)s;
            }
        }
    }
}

// ---------------------------------------------------------------------------
// Layer 1: sum 8 i32 kc planes in i64 (exact) + psp conv + fused spike LIF.
// ---------------------------------------------------------------------------
__global__ __launch_bounds__(320) void redpsp1_kernel(
    const int* __restrict__ Pc, unsigned short* __restrict__ smask)
{
    __shared__ double zs[16][304];
    __shared__ double us[16][304];
    __shared__ double eps[100];
    int og = blockIdx.x, b = blockIdx.y;
    int o0 = og * 16;
    int tid = threadIdx.x;
    const double sc27 = 1.0 / 134217728.0;

    if (tid < 100) {
        double td = (double)tid;
        eps[tid] = (td / 10.0) * exp(1.0 - td / 10.0);
    }
    if (tid < T) {
        size_t col = (size_t)b * T + tid;
        #pragma unroll 4
        for (int ol = 0; ol < 16; ++ol) {
            int o = o0 + ol;
            size_t idx = (size_t)o * NCOLS + col;
            long long s = 0;
            #pragma unroll
            for (int c = 0; c < 8; ++c)
                s += (long long)Pc[(size_t)c * PPLC32 + idx];
            zs[ol][tid] = (double)s * sc27;
        }
    }
    __syncthreads();

    if (tid < T) {
        double sum[16];
        #pragma unroll
        for (int o = 0; o < 16; ++o) sum[o] = 0.0;
        int kmax = tid < 99 ? tid : 99;
        for (int k = 0; k <= kmax; ++k) {
            double e = eps[k];
            #pragma unroll
            for (int o = 0; o < 16; ++o)
                sum[o] = fma(e, zs[o][tid - k], sum[o]);
        }
        #pragma unroll
        for (int o = 0; o < 16; ++o) us[o][tid] = sum[o];
    }
    if (og == 25 && tid < T) {     // zero mask bits 416..447
        size_t col = (size_t)b * T + tid;
        *(unsigned*)((char*)smask + (col * 28 + 26) * 2) = 0u;
    }
    __syncthreads();

    if (tid < 64) {
        int l = tid;
        bool act = (l < 16) && (o0 + l < O1);
        const double alpha = exp(-0.5);
        const double A31   = exp(-15.5);
        const double c0    = -10.0 * exp(1.0);
        double E = 0.0, G = 0.0;
        unsigned hist = 0u;
        for (int t = 0; t < T; ++t) {
            double uval = act ? us[l][t] : -1.0e300;
            double v = uval + c0 * G;
            bool sp = (v >= 10.0);
            unsigned long long bal = __ballot(sp);
            if (l == 0)
                smask[((size_t)b * T + t) * 28 + og] =
                    (unsigned short)(bal & 0xFFFFu);
            double sN  = sp ? 1.0 : 0.0;
            double s31 = ((hist >> 30) & 1u) ? 1.0 : 0.0;
            double Em  = E - A31 * s31;
            double Gm  = G - 31.0 * A31 * s31;
            G = alpha * (sN + Gm + Em);
            E = alpha * (sN + Em);
            hist = (hist << 1) | (sp ? 1u : 0u);
        }
    }
}

// ---------------------------------------------------------------------------
// Layers 2/3: reduce (i32 z, scale) + psp conv + fused spike.
// ---------------------------------------------------------------------------
template<int OPAD_, int O_, int SLOTS, int NOG, bool OUT>
__global__ __launch_bounds__(320) void redpsp23_kernel(
    const int* __restrict__ Z, unsigned short* __restrict__ smask,
    float* __restrict__ sout, double scale)
{
    __shared__ double zs[16][304];
    __shared__ double us[16][304];
    __shared__ double eps[100];
    int og = blockIdx.x, b = blockIdx.y;
    int o0 = og * 16;
    int tid = threadIdx.x;

    if (tid < 100) {
        double td = (double)tid;
        eps[tid] = (td / 10.0) * exp(1.0 - td / 10.0);
    }
    if (tid < T) {
        size_t col = (size_t)b * T + tid;
        #pragma unroll 4
        for (int ol = 0; ol < 16; ++ol) {
            int o = o0 + ol;
            double zv = (o < OPAD_) ? (double)Z[col * OPAD_ + o] * scale : 0.0;
            zs[ol][tid] = zv;
        }
    }
    __syncthreads();

    if (tid < T) {
        double sum[16];
        #pragma unroll
        for (int o = 0; o < 16; ++o) sum[o] = 0.0;
        int kmax = tid < 99 ? tid : 99;
        for (int k = 0; k <= kmax; ++k) {
            double e = eps[k];
            #pragma unroll
            for (int o = 0; o < 16; ++o)
                sum[o] = fma(e, zs[o][tid - k], sum[o]);
        }
        #pragma unroll
        for (int o = 0; o < 16; ++o) us[o][tid] = sum[o];
    }
    if (SLOTS > NOG && og == NOG - 1 && tid < T) {
        size_t col = (size_t)b * T + tid;
        #pragma unroll
        for (int s = NOG; s < SLOTS; ++s)
            smask[col * SLOTS + s] = 0;
    }
    __syncthreads();

    if (tid < 64) {
        int l = tid;
        bool act = (l < 16) && (o0 + l < O_);
        const double alpha = exp(-0.5);
        const double A31   = exp(-15.5);
        const double c0    = -10.0 * exp(1.0);
        double E = 0.0, G = 0.0;
        unsigned hist = 0u;
        for (int t = 0; t < T; ++t) {
            double uval = act ? us[l][t] : -1.0e300;
            double v = uval + c0 * G;
            bool sp = (v >= 10.0);
            unsigned long long bal = __ballot(sp);
            if (SLOTS > 0 && l == 0)
                smask[((size_t)b * T + t) * SLOTS + og] =
                    (unsigned short)(bal & 0xFFFFu);
            if (OUT && act)
                sout[((size_t)b * O_ + o0 + l) * T + t] = sp ? 1.0f : 0.0f;
            double sN  = sp ? 1.0 : 0.0;
            double s31 = ((hist >> 30) & 1u) ? 1.0 : 0.0;
            double Em  = E - A31 * s31;
            double Gm  = G - 31.0 * A31 * s31;
            G = alpha * (sN + Gm + Em);
            E = alpha * (sN + Em);
            hist = (hist << 1) | (sp ? 1u : 0u);
        }
    }
}

// ---------------------------------------------------------------------------
// Sparse integer GEMM for layers 2/3 (proven).
// ---------------------------------------------------------------------------
__global__ __launch_bounds__(128) void sparse_gemm_kernel(
    const int* __restrict__ QT, const unsigned long long* __restrict__ cmask,
    int* __restrict__ Z, int OPAD, int W, int CW, int cshift)
{
    __shared__ int lf[LCAP];
    __shared__ int wsum[2];

    int chunk = blockIdx.x & ((1 << cshift) - 1);
    int col   = blockIdx.x >> cshift;
    int tid   = threadIdx.x;

    int wbase = col * W + chunk * CW;
    unsigned long long w0 = (2 * tid     < CW) ? cmask[wbase + 2 * tid]     : 0ULL;
    unsigned long long w1 = (2 * tid + 1 < CW) ? cmask[wbase + 2 * tid + 1] : 0ULL;
    int my = __popcll(w0) + __popcll(w1);

    int scan = my;
    #pragma unroll
    for (int d = 1; d < 64; d <<= 1) {
        int v = __shfl_up(scan, d);
        if ((tid & 63) >= d) scan += v;
    }
    if ((tid & 63) == 63) wsum[tid >> 6] = scan;
    __syncthreads();
    int off = ((tid >= 64) ? wsum[0] : 0) + scan - my;
    int n = wsum[0] + wsum[1];

    int f0e = (chunk * CW + 2 * tid) * 64;
    unsigned long long m = w0;
    while (m) {
        int bit = __ffsll(m) - 1;
        if (off < LCAP) lf[off] = (f0e + bit) * OPAD;
        ++off; m &= m - 1;
    }
    m = w1; f0e += 64;
    while (m) {
        int bit = __ffsll(m) - 1;
        if (off < LCAP) lf[off] = (f0e + bit) * OPAD;
        ++off; m &= m - 1;
    }
    __syncthreads();
    if (n > LCAP) n = LCAP;

    if (tid * 4 < OPAD) {
        int o = tid * 4;
        const int* bq = QT + o;
        int a0 = 0, a1 = 0, a2 = 0, a3 = 0;
        int i = 0;
        for (; i + 8 <= n; i += 8) {
            int4 ia = *(const int4*)&lf[i];
            int4 ib = *(const int4*)&lf[i + 4];
            int e0 = __builtin_amdgcn_readfirstlane(ia.x);
            int e1 = __builtin_amdgcn_readfirstlane(ia.y);
            int e2 = __builtin_amdgcn_readfirstlane(ia.z);
            int e3 = __builtin_amdgcn_readfirstlane(ia.w);
            int e4 = __builtin_amdgcn_readfirstlane(ib.x);
            int e5 = __builtin_amdgcn_readfirstlane(ib.y);
            int e6 = __builtin_amdgcn_readfirstlane(ib.z);
            int e7 = __builtin_amdgcn_readfirstlane(ib.w);
            int4 q0 = *(const int4*)(bq + e0);
            int4 q1 = *(const int4*)(bq + e1);
            int4 q2 = *(const int4*)(bq + e2);
            int4 q3 = *(const int4*)(bq + e3);
            int4 q4 = *(const int4*)(bq + e4);
            int4 q5 = *(const int4*)(bq + e5);
            int4 q6 = *(const int4*)(bq + e6);
            int4 q7 = *(const int4*)(bq + e7);
            a0 += q0.x; a1 += q0.y; a2 += q0.z; a3 += q0.w;
            a0 += q1.x; a1 += q1.y; a2 += q1.z; a3 += q1.w;
            a0 += q2.x; a1 += q2.y; a2 += q2.z; a3 += q2.w;
            a0 += q3.x; a1 += q3.y; a2 += q3.z; a3 += q3.w;
            a0 += q4.x; a1 += q4.y; a2 += q4.z; a3 += q4.w;
            a0 += q5.x; a1 += q5.y; a2 += q5.z; a3 += q5.w;
            a0 += q6.x; a1 += q6.y; a2 += q6.z; a3 += q6.w;
            a0 += q7.x; a1 += q7.y; a2 += q7.z; a3 += q7.w;
        }
        for (; i < n; ++i) {
            int e = __builtin_amdgcn_readfirstlane(lf[i]);
            int4 q = *(const int4*)(bq + e);
            a0 += q.x; a1 += q.y; a2 += q.z; a3 += q.w;
        }
        int* zb = Z + ((size_t)chunk * NCOLS + col) * OPAD + o;
        *(int4*)zb = make_int4(a0, a1, a2, a3);
    }
}

// ---------------------------------------------------------------------------
extern "C" void kernel_launch(void* const* d_in, const int* in_sizes, int n_in,
                              void* d_out, int out_size, void* d_ws, size_t ws_size,
                              hipStream_t stream)
{
    const float* x  = (const float*)d_in[0];
    const float* W1 = (const float*)d_in[1];
    const float* W2 = (const float*)d_in[2];
    const float* W3 = (const float*)d_in[3];
    float* out = (float*)d_out;

    const size_t sz_Aswz   = (size_t)13 * 256 * 4 * 2048;      // 27.26 MB
    const size_t sz_Bbit   = (size_t)B * 256 * 320 * 4 * 2;    //  5.24 MB
    const size_t sz_Pc     = (size_t)8 * PPLC32 * 4;           // 31.95 MB
    const size_t sz_Q2T    = (size_t)O1 * OP2 * 4;
    const size_t sz_Q3T    = (size_t)O2 * OP3 * 4;
    const size_t sz_smask1 = (size_t)NCOLS * 28 * 2;           // 134 KB
    const size_t sz_smask2 = (size_t)NCOLS * 16 * 2;           //  77 KB

    char* p = (char*)d_ws;
    char*           Aswz   = p;                  p += sz_Aswz;
    unsigned short* Bbit   = (unsigned short*)p; p += sz_Bbit;
    int*            Pc     = (int*)p;  char* pa = p;  p += sz_Pc;
    int*            Q2T    = (int*)p;            p += sz_Q2T;
    int*            Q3T    = (int*)p;            p += sz_Q3T;
    unsigned short* smask1 = (unsigned short*)p; p += sz_smask1;
    unsigned short* smask2 = (unsigned short*)p; p += sz_smask2;
    // z2/z3 alias Pc's region (Pc dead after redpsp1):
    int* z2 = (int*)pa;                          pa += (size_t)NCOLS * OP2 * 4;
    int* z3 = (int*)pa;                          pa += (size_t)NCOLS * OP3 * 4;

    const double sc26 = 1.0 / 67108864.0;

    // --- prep (fused) ---
    prep_kernel<<<dim3(12304), dim3(256), 0, stream>>>(
        x, W1, W2, W3, Bbit, Aswz, Q2T, Q3T);

    // --- layer 1 (MFMA + fused psp/spike) ---
    mfma_gemm_kernel<<<dim3(1664), dim3(256), 0, stream>>>(Aswz, Bbit, Pc);
    redpsp1_kernel<<<dim3(26, B), dim3(320), 0, stream>>>(Pc, smask1);

    // --- layer 2 ---
    sparse_gemm_kernel<<<dim3(NCOLS), dim3(128), 0, stream>>>(
        Q2T, (const unsigned long long*)smask1, z2, OP2, W1M, W1M, 0);
    redpsp23_kernel<OP2, O2, 16, 15, false><<<dim3(15, B), dim3(320), 0, stream>>>(
        z2, smask2, (float*)0, sc26);

    // --- layer 3 ---
    sparse_gemm_kernel<<<dim3(NCOLS), dim3(128), 0, stream>>>(
        Q3T, (const unsigned long long*)smask2, z3, OP3, W2M, W2M, 0);
    redpsp23_kernel<OP3, O3, 0, 1, true><<<dim3(1, B), dim3(320), 0, stream>>>(
        z3, (unsigned short*)0, out, sc26);
}